// Round 5
// baseline (1305.951 us; speedup 1.0000x reference)
//
#include <hip/hip_runtime.h>
#include <hip/hip_bf16.h>

// MACE layer forward, MI355X (gfx950). f32 I/O, bf16 internals.
// Round 5: de-spill the MFMA edge kernel. One node per BLOCK (4 waves), each
// wave owns 2 of the 8 tile-groups -> per-lane acc state 32->8 regs, VGPR
// capped at 128 via __launch_bounds__(256,4). h stored interleaved
// [n][c][{s,v0,v1,v2}] so the per-edge gather is one 8B load (was 4x2B).
// R4 counters: VGPR=256, WRITE_SIZE=182MB (spills), occupancy 10% -> fix.

#define NN 10000
#define EE 320000
#define FEPS 0.17677669529663687f

typedef __attribute__((ext_vector_type(4))) float f32x4;
typedef __attribute__((ext_vector_type(8))) short s16x8;

__device__ __forceinline__ float bflo(unsigned u) { return __uint_as_float(u << 16); }
__device__ __forceinline__ float bfhi(unsigned u) { return __uint_as_float(u & 0xffff0000u); }
__device__ __forceinline__ float b2f(__hip_bfloat16 x) { return __bfloat162float(x); }
// round-to-nearest-even f32 -> bf16 bits
__device__ __forceinline__ unsigned short f2bu(float f) {
    unsigned u = __float_as_uint(f);
    return (unsigned short)((u + 0x7FFFu + ((u >> 16) & 1u)) >> 16);
}
__device__ __forceinline__ unsigned pack2(float a, float b) {
    return (unsigned)f2bu(a) | ((unsigned)f2bu(b) << 16);
}

// ---------------- CSR build ----------------
__global__ void k_hist(const int* __restrict__ recv, int* __restrict__ cnt) {
    int e = blockIdx.x * blockDim.x + threadIdx.x;
    if (e < EE) {
        int r = recv[e];
        r = ((unsigned)r < NN) ? r : 0;
        atomicAdd(&cnt[r], 1);
    }
}

__global__ void k_scan(const int* __restrict__ cnt, int* __restrict__ offs,
                       int* __restrict__ cur) {
    __shared__ int sums[1024];
    const int t = threadIdx.x;
    const int chunk = (NN + 1023) / 1024;  // 10
    const int start = t * chunk;
    int local = 0;
    for (int i = 0; i < chunk; i++) {
        int idx = start + i;
        if (idx < NN) local += cnt[idx];
    }
    sums[t] = local;
    __syncthreads();
    for (int ofs = 1; ofs < 1024; ofs <<= 1) {
        int u = (t >= ofs) ? sums[t - ofs] : 0;
        __syncthreads();
        sums[t] += u;
        __syncthreads();
    }
    int base = (t == 0) ? 0 : sums[t - 1];
    for (int i = 0; i < chunk; i++) {
        int idx = start + i;
        if (idx < NN) {
            offs[idx] = base;
            cur[idx] = base;
            base += cnt[idx];
        }
    }
    if (t == 0) offs[NN] = sums[1023];
}

__global__ void k_fill(const int* __restrict__ recv, int* __restrict__ cur,
                       int* __restrict__ csr) {
    int e = blockIdx.x * blockDim.x + threadIdx.x;
    if (e < EE) {
        int r = recv[e];
        r = ((unsigned)r < NN) ? r : 0;
        int slot = atomicAdd(&cur[r], 1);
        if ((unsigned)slot < EE) csr[slot] = e;
    }
}

// ---------------- transpose W_rad2 [64][640] f32 -> w2t [640][64] bf16 -----
__global__ void k_w2t(const float* __restrict__ W_rad2,
                      unsigned short* __restrict__ w2t) {
    int i = blockIdx.x * 256 + threadIdx.x;
    if (i < 640 * 64) {
        int n = i >> 6, k = i & 63;
        w2t[i] = f2bu(W_rad2[k * 640 + n]);
    }
}

// ---- node pre: h_s/h_v, interleaved bf16 out: h4[n][c] = {s,v0,v1,v2} ----
__global__ __launch_bounds__(512) void k_pre(
    const float* __restrict__ node_feats,
    const float* __restrict__ W_up_s,
    const float* __restrict__ W_up_v,
    uint2* __restrict__ h4) {
    const int sub = threadIdx.x >> 7, d = threadIdx.x & 127;
    const int n = blockIdx.x * 4 + sub;
    __shared__ float sv[4][512];
    const float* nf = node_feats + (size_t)n * 512;
    ((float4*)sv[sub])[d] = ((const float4*)nf)[d];
    __syncthreads();
    float as = 0.f, a0 = 0.f, a1 = 0.f, a2 = 0.f;
    for (int c = 0; c < 128; c++) {
        const float wus = W_up_s[c * 128 + d];
        const float wuv = W_up_v[c * 128 + d];
        as += sv[sub][c] * wus;
        a0 += sv[sub][128 + c * 3 + 0] * wuv;
        a1 += sv[sub][128 + c * 3 + 1] * wuv;
        a2 += sv[sub][128 + c * 3 + 2] * wuv;
    }
    h4[(size_t)n * 128 + d] = make_uint2(pack2(as, a0), pack2(a1, a2));
}

// ------- MFMA edge kernel: one node per block, 2 tile-groups per wave ------
__global__ __launch_bounds__(256, 4) void k_edge_mfma(
    const float* __restrict__ vectors,
    const float* __restrict__ radial,
    const int* __restrict__ senders,
    const float* __restrict__ W_rad1,
    const unsigned short* __restrict__ w2t,   // [640][64] bf16
    const uint2* __restrict__ h4,             // [N][128] {s,v0,v1,v2} bf16
    const int* __restrict__ offs, const int* __restrict__ csr,
    __hip_bfloat16* __restrict__ agg_g) {
    __shared__ unsigned short w1s[8 * 64];  // W_rad1 bf16, 1 KB
    const int tid = threadIdx.x;
    const int lane = tid & 63, wv = tid >> 6;
    for (int i = tid; i < 512; i += 256) w1s[i] = f2bu(W_rad1[i]);
    __syncthreads();
    const int n = blockIdx.x;
    const int start = offs[n];
    const int deg = offs[n + 1] - start;
    const int row = lane & 15, quad = lane >> 4;

    // this wave owns tile-groups 2*wv and 2*wv+1 (channels 16t+row)
    float acc_s[2], av0[2], av1[2], av2[2];
#pragma unroll
    for (int ti = 0; ti < 2; ti++) { acc_s[ti] = 0.f; av0[ti] = 0.f; av1[ti] = 0.f; av2[ti] = 0.f; }

    for (int g0 = 0; g0 < deg; g0 += 16) {
        // --- per-lane edge meta (edge = row; quads duplicate) ---
        int idx = start + g0 + row;
        int lim = start + deg - 1;
        int e = csr[idx < lim ? idx : lim];
        e = ((unsigned)e < EE) ? e : 0;
        int j = senders[e];
        j = ((unsigned)j < NN) ? j : 0;
        const float vx = vectors[e * 3 + 0];
        const float vy = vectors[e * 3 + 1];
        const float vz = vectors[e * 3 + 2];
        const float inr = 1.7320508075688772f /
                          (sqrtf(vx * vx + vy * vy + vz * vz) + 1e-9f);
        const float y0 = vx * inr, y1 = vy * inr, y2 = vz * inr;
        const float4 r0 = *(const float4*)(radial + (size_t)e * 8);
        const float4 r1 = *(const float4*)(radial + (size_t)e * 8 + 4);
        const float radv[8] = {r0.x, r0.y, r0.z, r0.w, r1.x, r1.y, r1.z, r1.w};
        // --- hid units quad*8..+7 and 32+quad*8..+7 for edge `row` ---
        float h0[8], h1[8];
#pragma unroll
        for (int u = 0; u < 8; u++) { h0[u] = 0.f; h1[u] = 0.f; }
#pragma unroll
        for (int r = 0; r < 8; r++) {
            const uint4 a = *(const uint4*)&w1s[r * 64 + quad * 8];
            const uint4 b = *(const uint4*)&w1s[r * 64 + 32 + quad * 8];
            const float rr = radv[r];
            h0[0] += rr * bflo(a.x); h0[1] += rr * bfhi(a.x);
            h0[2] += rr * bflo(a.y); h0[3] += rr * bfhi(a.y);
            h0[4] += rr * bflo(a.z); h0[5] += rr * bfhi(a.z);
            h0[6] += rr * bflo(a.w); h0[7] += rr * bfhi(a.w);
            h1[0] += rr * bflo(b.x); h1[1] += rr * bfhi(b.x);
            h1[2] += rr * bflo(b.y); h1[3] += rr * bfhi(b.y);
            h1[4] += rr * bflo(b.z); h1[5] += rr * bfhi(b.z);
            h1[6] += rr * bflo(b.w); h1[7] += rr * bfhi(b.w);
        }
        union { s16x8 v; unsigned short u[8]; } A0, A1;
#pragma unroll
        for (int u = 0; u < 8; u++) {
            A0.u[u] = f2bu(h0[u] / (1.f + __expf(-h0[u])));
            A1.u[u] = f2bu(h1[u] / (1.f + __expf(-h1[u])));
        }
        // --- broadcast meta for this quad's 4 C-rows ---
        int jr[4]; float yr0[4], yr1[4], yr2[4]; bool vr[4];
#pragma unroll
        for (int rg = 0; rg < 4; rg++) {
            const int src = quad * 4 + rg;
            jr[rg] = __shfl(j, src);
            yr0[rg] = __shfl(y0, src);
            yr1[rg] = __shfl(y1, src);
            yr2[rg] = __shfl(y2, src);
            vr[rg] = (g0 + src) < deg;
        }
        // --- this wave's 2 tile-groups ---
#pragma unroll
        for (int ti = 0; ti < 2; ti++) {
            const int t = 2 * wv + ti;
            f32x4 C[5];
#pragma unroll
            for (int p = 0; p < 5; p++) {
                const unsigned short* bp =
                    w2t + (size_t)(128 * p + 16 * t + row) * 64 + quad * 8;
                const s16x8 B0 = *(const s16x8*)(bp);
                const s16x8 B1 = *(const s16x8*)(bp + 32);
                f32x4 z = {0.f, 0.f, 0.f, 0.f};
                z = __builtin_amdgcn_mfma_f32_16x16x32_bf16(A0.v, B0, z, 0, 0, 0);
                z = __builtin_amdgcn_mfma_f32_16x16x32_bf16(A1.v, B1, z, 0, 0, 0);
                C[p] = z;
            }
            const int c = 16 * t + row;
#pragma unroll
            for (int rg = 0; rg < 4; rg++) {
                if (vr[rg]) {
                    const uint2 hh = h4[(size_t)jr[rg] * 128 + c];
                    const float sj = bflo(hh.x), a0 = bfhi(hh.x);
                    const float a1 = bflo(hh.y), a2 = bfhi(hh.y);
                    const float w0 = C[0][rg], w1p = C[1][rg], w2p = C[2][rg];
                    const float w3 = C[3][rg], w4 = C[4][rg];
                    const float d = a0 * yr0[rg] + a1 * yr1[rg] + a2 * yr2[rg];
                    const float cr0 = a1 * yr2[rg] - a2 * yr1[rg];
                    const float cr1 = a2 * yr0[rg] - a0 * yr2[rg];
                    const float cr2 = a0 * yr1[rg] - a1 * yr0[rg];
                    acc_s[ti] += w0 * sj + w3 * d;
                    av0[ti] += w1p * sj * yr0[rg] + w2p * a0 + w4 * cr0;
                    av1[ti] += w1p * sj * yr1[rg] + w2p * a1 + w4 * cr1;
                    av2[ti] += w1p * sj * yr2[rg] + w2p * a2 + w4 * cr2;
                }
            }
        }
    }
    // --- cross-quad reduction (C-rows live in different quads) ---
#pragma unroll
    for (int ti = 0; ti < 2; ti++) {
        acc_s[ti] += __shfl_xor(acc_s[ti], 16); acc_s[ti] += __shfl_xor(acc_s[ti], 32);
        av0[ti] += __shfl_xor(av0[ti], 16);     av0[ti] += __shfl_xor(av0[ti], 32);
        av1[ti] += __shfl_xor(av1[ti], 16);     av1[ti] += __shfl_xor(av1[ti], 32);
        av2[ti] += __shfl_xor(av2[ti], 16);     av2[ti] += __shfl_xor(av2[ti], 32);
    }
    if (lane < 16) {
        unsigned short* og = (unsigned short*)agg_g + (size_t)n * 512;
#pragma unroll
        for (int ti = 0; ti < 2; ti++) {
            const int c = 16 * (2 * wv + ti) + lane;
            og[c] = f2bu(acc_s[ti]);
            og[128 + 3 * c + 0] = f2bu(av0[ti]);
            og[128 + 3 * c + 1] = f2bu(av1[ti]);
            og[128 + 3 * c + 2] = f2bu(av2[ti]);
        }
    }
}

// ---------------- node post: down/prod/lin/skip/readout ----------------
__global__ __launch_bounds__(512) void k_post(
    const float* __restrict__ node_feats,
    const int* __restrict__ specie,
    const __hip_bfloat16* __restrict__ agg_g,
    const float* __restrict__ W_down_s,
    const float* __restrict__ W_down_v,
    const float* __restrict__ W_skip_s,
    const float* __restrict__ W_skip_v,
    const float* __restrict__ W_prod_s,
    const float* __restrict__ W_prod_v,
    const float* __restrict__ W_lin_s,
    const float* __restrict__ W_lin_v,
    const float* __restrict__ W_ro,
    float* __restrict__ d_out) {
    const int sub = threadIdx.x >> 7, d = threadIdx.x & 127;
    const int n = blockIdx.x * 4 + sub;
    __shared__ float sv[4][512];
    __shared__ float ag[4][512];
    __shared__ float pl[4][512];
    __shared__ float red[4][2];
    const float* nf = node_feats + (size_t)n * 512;
    const __hip_bfloat16* agp = agg_g + (size_t)n * 512;
    ((float4*)sv[sub])[d] = ((const float4*)nf)[d];
    for (int i = d; i < 512; i += 128) ag[sub][i] = b2f(agp[i]);
    __syncthreads();
    int spec = specie[n];
    spec = ((unsigned)spec < 10) ? spec : 0;
    const float* Wss = W_skip_s + (size_t)spec * 16384;
    const float* Wsv = W_skip_v + (size_t)spec * 16384;
    float scs = 0, scv0 = 0, scv1 = 0, scv2 = 0, fs = 0, fv0 = 0, fv1 = 0, fv2 = 0;
    for (int c = 0; c < 128; c++) {
        const float s_c = sv[sub][c];
        const float v0 = sv[sub][128 + c * 3 + 0];
        const float v1 = sv[sub][128 + c * 3 + 1];
        const float v2 = sv[sub][128 + c * 3 + 2];
        const float a_c = ag[sub][c];
        const float a0 = ag[sub][128 + c * 3 + 0];
        const float a1 = ag[sub][128 + c * 3 + 1];
        const float a2 = ag[sub][128 + c * 3 + 2];
        const float wss = Wss[c * 128 + d];
        const float wsv = Wsv[c * 128 + d];
        const float wds = W_down_s[c * 128 + d];
        const float wdv = W_down_v[c * 128 + d];
        scs += s_c * wss;
        scv0 += v0 * wsv; scv1 += v1 * wsv; scv2 += v2 * wsv;
        fs += a_c * wds;
        fv0 += a0 * wdv; fv1 += a1 * wdv; fv2 += a2 * wdv;
    }
    fs *= FEPS; fv0 *= FEPS; fv1 *= FEPS; fv2 *= FEPS;
    const float ps = fs * W_prod_s[spec * 384 + d]
                   + fs * fs * W_prod_s[spec * 384 + 128 + d]
                   + (fv0 * fv0 + fv1 * fv1 + fv2 * fv2) * W_prod_s[spec * 384 + 256 + d];
    const float pw0 = W_prod_v[spec * 256 + d];
    const float pw1 = W_prod_v[spec * 256 + 128 + d];
    const float pv0 = fv0 * pw0 + fs * fv0 * pw1;
    const float pv1 = fv1 * pw0 + fs * fv1 * pw1;
    const float pv2 = fv2 * pw0 + fs * fv2 * pw1;
    pl[sub][d] = ps;
    pl[sub][128 + d * 3 + 0] = pv0;
    pl[sub][128 + d * 3 + 1] = pv1;
    pl[sub][128 + d * 3 + 2] = pv2;
    __syncthreads();
    float outs = scs, ov0 = scv0, ov1 = scv1, ov2 = scv2;
    for (int c = 0; c < 128; c++) {
        const float wls = W_lin_s[c * 128 + d];
        const float wlv = W_lin_v[c * 128 + d];
        outs += pl[sub][c] * wls;
        ov0 += pl[sub][128 + c * 3 + 0] * wlv;
        ov1 += pl[sub][128 + c * 3 + 1] * wlv;
        ov2 += pl[sub][128 + c * 3 + 2] * wlv;
    }
    float* o1 = d_out + NN + (size_t)n * 512;
    o1[d] = outs;
    o1[128 + d * 3 + 0] = ov0;
    o1[128 + d * 3 + 1] = ov1;
    o1[128 + d * 3 + 2] = ov2;
    float r = outs * W_ro[d];
#pragma unroll
    for (int o = 32; o > 0; o >>= 1) r += __shfl_down(r, o);
    const int lane = threadIdx.x & 63;
    const int wv_in_sub = (threadIdx.x >> 6) & 1;
    if (lane == 0) red[sub][wv_in_sub] = r;
    __syncthreads();
    if (d == 0) d_out[n] = red[sub][0] + red[sub][1];
}

extern "C" void kernel_launch(void* const* d_in, const int* in_sizes, int n_in,
                              void* d_out, int out_size, void* d_ws, size_t ws_size,
                              hipStream_t stream) {
    const float* vectors    = (const float*)d_in[0];
    const float* node_feats = (const float*)d_in[1];
    const int*   specie     = (const int*)d_in[2];
    const float* radial     = (const float*)d_in[3];
    const int*   senders    = (const int*)d_in[4];
    const int*   receivers  = (const int*)d_in[5];
    const float* W_up_s     = (const float*)d_in[6];
    const float* W_up_v     = (const float*)d_in[7];
    const float* W_rad1     = (const float*)d_in[8];
    const float* W_rad2     = (const float*)d_in[9];
    const float* W_down_s   = (const float*)d_in[10];
    const float* W_down_v   = (const float*)d_in[11];
    const float* W_skip_s   = (const float*)d_in[12];
    const float* W_skip_v   = (const float*)d_in[13];
    const float* W_prod_s   = (const float*)d_in[14];
    const float* W_prod_v   = (const float*)d_in[15];
    const float* W_lin_s    = (const float*)d_in[16];
    const float* W_lin_v    = (const float*)d_in[17];
    const float* W_ro       = (const float*)d_in[18];
    float* out = (float*)d_out;

    // workspace carve (~22.2 MB): CSR first, interleaved h4, bf16 agg, w2t
    char* w = (char*)d_ws;
    auto align256 = [](size_t x) { return (x + 255) & ~(size_t)255; };
    int* cnt  = (int*)w;              w += align256((size_t)NN * 4);
    int* offs = (int*)w;              w += align256((size_t)(NN + 1) * 4);
    int* cur  = (int*)w;              w += align256((size_t)NN * 4);
    int* csr  = (int*)w;              w += align256((size_t)EE * 4);
    uint2* h4 = (uint2*)w;            w += align256((size_t)NN * 128 * 8);
    __hip_bfloat16* agg_g = (__hip_bfloat16*)w;  w += align256((size_t)NN * 512 * 2);
    unsigned short* w2t   = (unsigned short*)w;  // 640*64*2 = 80 KB

    hipMemsetAsync(cnt, 0, NN * sizeof(int), stream);
    k_hist<<<(EE + 255) / 256, 256, 0, stream>>>(receivers, cnt);
    k_scan<<<1, 1024, 0, stream>>>(cnt, offs, cur);
    k_fill<<<(EE + 255) / 256, 256, 0, stream>>>(receivers, cur, csr);
    k_w2t<<<160, 256, 0, stream>>>(W_rad2, w2t);
    k_pre<<<NN / 4, 512, 0, stream>>>(node_feats, W_up_s, W_up_v, h4);
    k_edge_mfma<<<NN, 256, 0, stream>>>(vectors, radial, senders, W_rad1,
                                        w2t, h4, offs, csr, agg_g);
    k_post<<<NN / 4, 512, 0, stream>>>(node_feats, specie, agg_g,
                                       W_down_s, W_down_v, W_skip_s, W_skip_v,
                                       W_prod_s, W_prod_v, W_lin_s, W_lin_v,
                                       W_ro, out);
}

// Round 6
// 804.815 us; speedup vs baseline: 1.6227x; 1.6227x over previous
//
#include <hip/hip_runtime.h>
#include <hip/hip_bf16.h>

// MACE layer forward, MI355X (gfx950). f32 I/O, bf16 internals.
// Round 6: kill the spills. R5 counters: VGPR=64 (launch_bounds(256,4)
// empirically caps at 256/4!), WRITE_SIZE=1.66GB = scratch spill traffic,
// hbm 51% peak -> spill-bandwidth-bound. Changes:
//  - B-frags (w2t) are edge-invariant -> hoisted out of the loop into 80
//    VGPRs, loaded once per block (also deletes the 1.6GB w2t re-read).
//  - per-p immediate C consumption (C live: 20 regs -> 4).
//  - __launch_bounds__(256) only; let the allocator take ~150-200 VGPRs.

#define NN 10000
#define EE 320000
#define FEPS 0.17677669529663687f

typedef __attribute__((ext_vector_type(4))) float f32x4;
typedef __attribute__((ext_vector_type(8))) short s16x8;

__device__ __forceinline__ float bflo(unsigned u) { return __uint_as_float(u << 16); }
__device__ __forceinline__ float bfhi(unsigned u) { return __uint_as_float(u & 0xffff0000u); }
__device__ __forceinline__ float b2f(__hip_bfloat16 x) { return __bfloat162float(x); }
// round-to-nearest-even f32 -> bf16 bits
__device__ __forceinline__ unsigned short f2bu(float f) {
    unsigned u = __float_as_uint(f);
    return (unsigned short)((u + 0x7FFFu + ((u >> 16) & 1u)) >> 16);
}
__device__ __forceinline__ unsigned pack2(float a, float b) {
    return (unsigned)f2bu(a) | ((unsigned)f2bu(b) << 16);
}

// ---------------- CSR build ----------------
__global__ void k_hist(const int* __restrict__ recv, int* __restrict__ cnt) {
    int e = blockIdx.x * blockDim.x + threadIdx.x;
    if (e < EE) {
        int r = recv[e];
        r = ((unsigned)r < NN) ? r : 0;
        atomicAdd(&cnt[r], 1);
    }
}

__global__ void k_scan(const int* __restrict__ cnt, int* __restrict__ offs,
                       int* __restrict__ cur) {
    __shared__ int sums[1024];
    const int t = threadIdx.x;
    const int chunk = (NN + 1023) / 1024;  // 10
    const int start = t * chunk;
    int local = 0;
    for (int i = 0; i < chunk; i++) {
        int idx = start + i;
        if (idx < NN) local += cnt[idx];
    }
    sums[t] = local;
    __syncthreads();
    for (int ofs = 1; ofs < 1024; ofs <<= 1) {
        int u = (t >= ofs) ? sums[t - ofs] : 0;
        __syncthreads();
        sums[t] += u;
        __syncthreads();
    }
    int base = (t == 0) ? 0 : sums[t - 1];
    for (int i = 0; i < chunk; i++) {
        int idx = start + i;
        if (idx < NN) {
            offs[idx] = base;
            cur[idx] = base;
            base += cnt[idx];
        }
    }
    if (t == 0) offs[NN] = sums[1023];
}

__global__ void k_fill(const int* __restrict__ recv, int* __restrict__ cur,
                       int* __restrict__ csr) {
    int e = blockIdx.x * blockDim.x + threadIdx.x;
    if (e < EE) {
        int r = recv[e];
        r = ((unsigned)r < NN) ? r : 0;
        int slot = atomicAdd(&cur[r], 1);
        if ((unsigned)slot < EE) csr[slot] = e;
    }
}

// ---------------- transpose W_rad2 [64][640] f32 -> w2t [640][64] bf16 -----
__global__ void k_w2t(const float* __restrict__ W_rad2,
                      unsigned short* __restrict__ w2t) {
    int i = blockIdx.x * 256 + threadIdx.x;
    if (i < 640 * 64) {
        int n = i >> 6, k = i & 63;
        w2t[i] = f2bu(W_rad2[k * 640 + n]);
    }
}

// ---- node pre: h_s/h_v, interleaved bf16 out: h4[n][c] = {s,v0,v1,v2} ----
__global__ __launch_bounds__(512) void k_pre(
    const float* __restrict__ node_feats,
    const float* __restrict__ W_up_s,
    const float* __restrict__ W_up_v,
    uint2* __restrict__ h4) {
    const int sub = threadIdx.x >> 7, d = threadIdx.x & 127;
    const int n = blockIdx.x * 4 + sub;
    __shared__ float sv[4][512];
    const float* nf = node_feats + (size_t)n * 512;
    ((float4*)sv[sub])[d] = ((const float4*)nf)[d];
    __syncthreads();
    float as = 0.f, a0 = 0.f, a1 = 0.f, a2 = 0.f;
    for (int c = 0; c < 128; c++) {
        const float wus = W_up_s[c * 128 + d];
        const float wuv = W_up_v[c * 128 + d];
        as += sv[sub][c] * wus;
        a0 += sv[sub][128 + c * 3 + 0] * wuv;
        a1 += sv[sub][128 + c * 3 + 1] * wuv;
        a2 += sv[sub][128 + c * 3 + 2] * wuv;
    }
    h4[(size_t)n * 128 + d] = make_uint2(pack2(as, a0), pack2(a1, a2));
}

// ------- MFMA edge kernel: one node per block, 2 tile-groups per wave ------
__global__ __launch_bounds__(256) void k_edge_mfma(
    const float* __restrict__ vectors,
    const float* __restrict__ radial,
    const int* __restrict__ senders,
    const float* __restrict__ W_rad1,
    const unsigned short* __restrict__ w2t,   // [640][64] bf16
    const uint2* __restrict__ h4,             // [N][128] {s,v0,v1,v2} bf16
    const int* __restrict__ offs, const int* __restrict__ csr,
    __hip_bfloat16* __restrict__ agg_g) {
    __shared__ unsigned short w1s[8 * 64];  // W_rad1 bf16, 1 KB
    const int tid = threadIdx.x;
    const int lane = tid & 63, wv = tid >> 6;
    for (int i = tid; i < 512; i += 256) w1s[i] = f2bu(W_rad1[i]);
    __syncthreads();
    const int n = blockIdx.x;
    const int start = offs[n];
    const int deg = offs[n + 1] - start;
    const int row = lane & 15, quad = lane >> 4;

    // --- hoist B-frags: invariant across edges; 20 frags = 80 VGPRs ---
    s16x8 Bf[2][5][2];
#pragma unroll
    for (int ti = 0; ti < 2; ti++) {
        const int t = 2 * wv + ti;
#pragma unroll
        for (int p = 0; p < 5; p++) {
            const unsigned short* bp =
                w2t + (size_t)(128 * p + 16 * t + row) * 64 + quad * 8;
            Bf[ti][p][0] = *(const s16x8*)(bp);
            Bf[ti][p][1] = *(const s16x8*)(bp + 32);
        }
    }

    float acc_s[2], av0[2], av1[2], av2[2];
#pragma unroll
    for (int ti = 0; ti < 2; ti++) { acc_s[ti] = 0.f; av0[ti] = 0.f; av1[ti] = 0.f; av2[ti] = 0.f; }

    for (int g0 = 0; g0 < deg; g0 += 16) {
        // --- per-lane edge meta (edge = row; quads duplicate) ---
        int idx = start + g0 + row;
        int lim = start + deg - 1;
        int e = csr[idx < lim ? idx : lim];
        e = ((unsigned)e < EE) ? e : 0;
        int j = senders[e];
        j = ((unsigned)j < NN) ? j : 0;
        const float vx = vectors[e * 3 + 0];
        const float vy = vectors[e * 3 + 1];
        const float vz = vectors[e * 3 + 2];
        const float inr = 1.7320508075688772f /
                          (sqrtf(vx * vx + vy * vy + vz * vz) + 1e-9f);
        const float y0 = vx * inr, y1 = vy * inr, y2 = vz * inr;
        const float4 r0 = *(const float4*)(radial + (size_t)e * 8);
        const float4 r1 = *(const float4*)(radial + (size_t)e * 8 + 4);
        const float radv[8] = {r0.x, r0.y, r0.z, r0.w, r1.x, r1.y, r1.z, r1.w};
        // --- hid units quad*8..+7 and 32+quad*8..+7 for edge `row` ---
        float h0[8], h1[8];
#pragma unroll
        for (int u = 0; u < 8; u++) { h0[u] = 0.f; h1[u] = 0.f; }
#pragma unroll
        for (int r = 0; r < 8; r++) {
            const uint4 a = *(const uint4*)&w1s[r * 64 + quad * 8];
            const uint4 b = *(const uint4*)&w1s[r * 64 + 32 + quad * 8];
            const float rr = radv[r];
            h0[0] += rr * bflo(a.x); h0[1] += rr * bfhi(a.x);
            h0[2] += rr * bflo(a.y); h0[3] += rr * bfhi(a.y);
            h0[4] += rr * bflo(a.z); h0[5] += rr * bfhi(a.z);
            h0[6] += rr * bflo(a.w); h0[7] += rr * bfhi(a.w);
            h1[0] += rr * bflo(b.x); h1[1] += rr * bfhi(b.x);
            h1[2] += rr * bflo(b.y); h1[3] += rr * bfhi(b.y);
            h1[4] += rr * bflo(b.z); h1[5] += rr * bfhi(b.z);
            h1[6] += rr * bflo(b.w); h1[7] += rr * bfhi(b.w);
        }
        union { s16x8 v; unsigned short u[8]; } A0, A1;
#pragma unroll
        for (int u = 0; u < 8; u++) {
            A0.u[u] = f2bu(h0[u] / (1.f + __expf(-h0[u])));
            A1.u[u] = f2bu(h1[u] / (1.f + __expf(-h1[u])));
        }
        // --- broadcast meta for this quad's 4 C-rows ---
        int jr[4]; float yr0[4], yr1[4], yr2[4];
#pragma unroll
        for (int rg = 0; rg < 4; rg++) {
            const int src = quad * 4 + rg;
            jr[rg] = __shfl(j, src);
            yr0[rg] = __shfl(y0, src);
            yr1[rg] = __shfl(y1, src);
            yr2[rg] = __shfl(y2, src);
        }
        // --- this wave's 2 tile-groups; per-p immediate C consumption ---
#pragma unroll
        for (int ti = 0; ti < 2; ti++) {
            const int t = 2 * wv + ti;
            const int c = 16 * t + row;
            // basis per rg (mask invalid rows by zeroing the basis)
            float sj[4], a0r[4], a1r[4], a2r[4], dotr[4], cr0[4], cr1[4], cr2[4];
#pragma unroll
            for (int rg = 0; rg < 4; rg++) {
                const bool ok = (g0 + quad * 4 + rg) < deg;
                const uint2 hh = h4[(size_t)jr[rg] * 128 + c];
                const float s_ = ok ? bflo(hh.x) : 0.f;
                const float a0 = ok ? bfhi(hh.x) : 0.f;
                const float a1 = ok ? bflo(hh.y) : 0.f;
                const float a2 = ok ? bfhi(hh.y) : 0.f;
                sj[rg] = s_; a0r[rg] = a0; a1r[rg] = a1; a2r[rg] = a2;
                dotr[rg] = a0 * yr0[rg] + a1 * yr1[rg] + a2 * yr2[rg];
                cr0[rg] = a1 * yr2[rg] - a2 * yr1[rg];
                cr1[rg] = a2 * yr0[rg] - a0 * yr2[rg];
                cr2[rg] = a0 * yr1[rg] - a1 * yr0[rg];
            }
#pragma unroll
            for (int p = 0; p < 5; p++) {
                f32x4 z = {0.f, 0.f, 0.f, 0.f};
                z = __builtin_amdgcn_mfma_f32_16x16x32_bf16(A0.v, Bf[ti][p][0], z, 0, 0, 0);
                z = __builtin_amdgcn_mfma_f32_16x16x32_bf16(A1.v, Bf[ti][p][1], z, 0, 0, 0);
#pragma unroll
                for (int rg = 0; rg < 4; rg++) {
                    const float w = z[rg];
                    if (p == 0) {
                        acc_s[ti] += w * sj[rg];
                    } else if (p == 1) {
                        const float ws = w * sj[rg];
                        av0[ti] += ws * yr0[rg];
                        av1[ti] += ws * yr1[rg];
                        av2[ti] += ws * yr2[rg];
                    } else if (p == 2) {
                        av0[ti] += w * a0r[rg];
                        av1[ti] += w * a1r[rg];
                        av2[ti] += w * a2r[rg];
                    } else if (p == 3) {
                        acc_s[ti] += w * dotr[rg];
                    } else {
                        av0[ti] += w * cr0[rg];
                        av1[ti] += w * cr1[rg];
                        av2[ti] += w * cr2[rg];
                    }
                }
            }
        }
    }
    // --- cross-quad reduction (C-rows live in different quads) ---
#pragma unroll
    for (int ti = 0; ti < 2; ti++) {
        acc_s[ti] += __shfl_xor(acc_s[ti], 16); acc_s[ti] += __shfl_xor(acc_s[ti], 32);
        av0[ti] += __shfl_xor(av0[ti], 16);     av0[ti] += __shfl_xor(av0[ti], 32);
        av1[ti] += __shfl_xor(av1[ti], 16);     av1[ti] += __shfl_xor(av1[ti], 32);
        av2[ti] += __shfl_xor(av2[ti], 16);     av2[ti] += __shfl_xor(av2[ti], 32);
    }
    if (lane < 16) {
        unsigned short* og = (unsigned short*)agg_g + (size_t)n * 512;
#pragma unroll
        for (int ti = 0; ti < 2; ti++) {
            const int c = 16 * (2 * wv + ti) + lane;
            og[c] = f2bu(acc_s[ti]);
            og[128 + 3 * c + 0] = f2bu(av0[ti]);
            og[128 + 3 * c + 1] = f2bu(av1[ti]);
            og[128 + 3 * c + 2] = f2bu(av2[ti]);
        }
    }
}

// ---------------- node post: down/prod/lin/skip/readout ----------------
__global__ __launch_bounds__(512) void k_post(
    const float* __restrict__ node_feats,
    const int* __restrict__ specie,
    const __hip_bfloat16* __restrict__ agg_g,
    const float* __restrict__ W_down_s,
    const float* __restrict__ W_down_v,
    const float* __restrict__ W_skip_s,
    const float* __restrict__ W_skip_v,
    const float* __restrict__ W_prod_s,
    const float* __restrict__ W_prod_v,
    const float* __restrict__ W_lin_s,
    const float* __restrict__ W_lin_v,
    const float* __restrict__ W_ro,
    float* __restrict__ d_out) {
    const int sub = threadIdx.x >> 7, d = threadIdx.x & 127;
    const int n = blockIdx.x * 4 + sub;
    __shared__ float sv[4][512];
    __shared__ float ag[4][512];
    __shared__ float pl[4][512];
    __shared__ float red[4][2];
    const float* nf = node_feats + (size_t)n * 512;
    const __hip_bfloat16* agp = agg_g + (size_t)n * 512;
    ((float4*)sv[sub])[d] = ((const float4*)nf)[d];
    for (int i = d; i < 512; i += 128) ag[sub][i] = b2f(agp[i]);
    __syncthreads();
    int spec = specie[n];
    spec = ((unsigned)spec < 10) ? spec : 0;
    const float* Wss = W_skip_s + (size_t)spec * 16384;
    const float* Wsv = W_skip_v + (size_t)spec * 16384;
    float scs = 0, scv0 = 0, scv1 = 0, scv2 = 0, fs = 0, fv0 = 0, fv1 = 0, fv2 = 0;
    for (int c = 0; c < 128; c++) {
        const float s_c = sv[sub][c];
        const float v0 = sv[sub][128 + c * 3 + 0];
        const float v1 = sv[sub][128 + c * 3 + 1];
        const float v2 = sv[sub][128 + c * 3 + 2];
        const float a_c = ag[sub][c];
        const float a0 = ag[sub][128 + c * 3 + 0];
        const float a1 = ag[sub][128 + c * 3 + 1];
        const float a2 = ag[sub][128 + c * 3 + 2];
        const float wss = Wss[c * 128 + d];
        const float wsv = Wsv[c * 128 + d];
        const float wds = W_down_s[c * 128 + d];
        const float wdv = W_down_v[c * 128 + d];
        scs += s_c * wss;
        scv0 += v0 * wsv; scv1 += v1 * wsv; scv2 += v2 * wsv;
        fs += a_c * wds;
        fv0 += a0 * wdv; fv1 += a1 * wdv; fv2 += a2 * wdv;
    }
    fs *= FEPS; fv0 *= FEPS; fv1 *= FEPS; fv2 *= FEPS;
    const float ps = fs * W_prod_s[spec * 384 + d]
                   + fs * fs * W_prod_s[spec * 384 + 128 + d]
                   + (fv0 * fv0 + fv1 * fv1 + fv2 * fv2) * W_prod_s[spec * 384 + 256 + d];
    const float pw0 = W_prod_v[spec * 256 + d];
    const float pw1 = W_prod_v[spec * 256 + 128 + d];
    const float pv0 = fv0 * pw0 + fs * fv0 * pw1;
    const float pv1 = fv1 * pw0 + fs * fv1 * pw1;
    const float pv2 = fv2 * pw0 + fs * fv2 * pw1;
    pl[sub][d] = ps;
    pl[sub][128 + d * 3 + 0] = pv0;
    pl[sub][128 + d * 3 + 1] = pv1;
    pl[sub][128 + d * 3 + 2] = pv2;
    __syncthreads();
    float outs = scs, ov0 = scv0, ov1 = scv1, ov2 = scv2;
    for (int c = 0; c < 128; c++) {
        const float wls = W_lin_s[c * 128 + d];
        const float wlv = W_lin_v[c * 128 + d];
        outs += pl[sub][c] * wls;
        ov0 += pl[sub][128 + c * 3 + 0] * wlv;
        ov1 += pl[sub][128 + c * 3 + 1] * wlv;
        ov2 += pl[sub][128 + c * 3 + 2] * wlv;
    }
    float* o1 = d_out + NN + (size_t)n * 512;
    o1[d] = outs;
    o1[128 + d * 3 + 0] = ov0;
    o1[128 + d * 3 + 1] = ov1;
    o1[128 + d * 3 + 2] = ov2;
    float r = outs * W_ro[d];
#pragma unroll
    for (int o = 32; o > 0; o >>= 1) r += __shfl_down(r, o);
    const int lane = threadIdx.x & 63;
    const int wv_in_sub = (threadIdx.x >> 6) & 1;
    if (lane == 0) red[sub][wv_in_sub] = r;
    __syncthreads();
    if (d == 0) d_out[n] = red[sub][0] + red[sub][1];
}

extern "C" void kernel_launch(void* const* d_in, const int* in_sizes, int n_in,
                              void* d_out, int out_size, void* d_ws, size_t ws_size,
                              hipStream_t stream) {
    const float* vectors    = (const float*)d_in[0];
    const float* node_feats = (const float*)d_in[1];
    const int*   specie     = (const int*)d_in[2];
    const float* radial     = (const float*)d_in[3];
    const int*   senders    = (const int*)d_in[4];
    const int*   receivers  = (const int*)d_in[5];
    const float* W_up_s     = (const float*)d_in[6];
    const float* W_up_v     = (const float*)d_in[7];
    const float* W_rad1     = (const float*)d_in[8];
    const float* W_rad2     = (const float*)d_in[9];
    const float* W_down_s   = (const float*)d_in[10];
    const float* W_down_v   = (const float*)d_in[11];
    const float* W_skip_s   = (const float*)d_in[12];
    const float* W_skip_v   = (const float*)d_in[13];
    const float* W_prod_s   = (const float*)d_in[14];
    const float* W_prod_v   = (const float*)d_in[15];
    const float* W_lin_s    = (const float*)d_in[16];
    const float* W_lin_v    = (const float*)d_in[17];
    const float* W_ro       = (const float*)d_in[18];
    float* out = (float*)d_out;

    // workspace carve (~22.2 MB): CSR first, interleaved h4, bf16 agg, w2t
    char* w = (char*)d_ws;
    auto align256 = [](size_t x) { return (x + 255) & ~(size_t)255; };
    int* cnt  = (int*)w;              w += align256((size_t)NN * 4);
    int* offs = (int*)w;              w += align256((size_t)(NN + 1) * 4);
    int* cur  = (int*)w;              w += align256((size_t)NN * 4);
    int* csr  = (int*)w;              w += align256((size_t)EE * 4);
    uint2* h4 = (uint2*)w;            w += align256((size_t)NN * 128 * 8);
    __hip_bfloat16* agg_g = (__hip_bfloat16*)w;  w += align256((size_t)NN * 512 * 2);
    unsigned short* w2t   = (unsigned short*)w;  // 640*64*2 = 80 KB

    hipMemsetAsync(cnt, 0, NN * sizeof(int), stream);
    k_hist<<<(EE + 255) / 256, 256, 0, stream>>>(receivers, cnt);
    k_scan<<<1, 1024, 0, stream>>>(cnt, offs, cur);
    k_fill<<<(EE + 255) / 256, 256, 0, stream>>>(receivers, cur, csr);
    k_w2t<<<160, 256, 0, stream>>>(W_rad2, w2t);
    k_pre<<<NN / 4, 512, 0, stream>>>(node_feats, W_up_s, W_up_v, h4);
    k_edge_mfma<<<NN, 256, 0, stream>>>(vectors, radial, senders, W_rad1,
                                        w2t, h4, offs, csr, agg_g);
    k_post<<<NN / 4, 512, 0, stream>>>(node_feats, specie, agg_g,
                                       W_down_s, W_down_v, W_skip_s, W_skip_v,
                                       W_prod_s, W_prod_v, W_lin_s, W_lin_v,
                                       W_ro, out);
}

// Round 7
// 621.088 us; speedup vs baseline: 2.1027x; 1.2958x over previous
//
#include <hip/hip_runtime.h>
#include <hip/hip_bf16.h>

// MACE layer forward, MI355X (gfx950). f32 I/O, bf16 internals.
// Round 7: degree-aware restructure of k_edge. Mean deg = 32 -> per-node
// fixed cost dominated. Changes: (1) grid-stride node loop, Bf/w1s loaded
// once per block; (2) cooperative 64-edge chunk staging: meta (j,y) + hid
// (computed ONCE, was duplicated x4 waves) into LDS; A-frags via
// ds_read_b128 (144B row stride -> 2-way conflicts only); (3) hid rows of
// invalid edges zeroed -> path weights exactly 0 -> no masks in inner loop.

#define NN 10000
#define EE 320000
#define FEPS 0.17677669529663687f

typedef __attribute__((ext_vector_type(4))) float f32x4;
typedef __attribute__((ext_vector_type(8))) short s16x8;

__device__ __forceinline__ float bflo(unsigned u) { return __uint_as_float(u << 16); }
__device__ __forceinline__ float bfhi(unsigned u) { return __uint_as_float(u & 0xffff0000u); }
__device__ __forceinline__ float b2f(__hip_bfloat16 x) { return __bfloat162float(x); }
// round-to-nearest-even f32 -> bf16 bits
__device__ __forceinline__ unsigned short f2bu(float f) {
    unsigned u = __float_as_uint(f);
    return (unsigned short)((u + 0x7FFFu + ((u >> 16) & 1u)) >> 16);
}
__device__ __forceinline__ unsigned pack2(float a, float b) {
    return (unsigned)f2bu(a) | ((unsigned)f2bu(b) << 16);
}

// ---------------- CSR build ----------------
__global__ void k_hist(const int* __restrict__ recv, int* __restrict__ cnt) {
    int e = blockIdx.x * blockDim.x + threadIdx.x;
    if (e < EE) {
        int r = recv[e];
        r = ((unsigned)r < NN) ? r : 0;
        atomicAdd(&cnt[r], 1);
    }
}

__global__ void k_scan(const int* __restrict__ cnt, int* __restrict__ offs,
                       int* __restrict__ cur) {
    __shared__ int sums[1024];
    const int t = threadIdx.x;
    const int chunk = (NN + 1023) / 1024;  // 10
    const int start = t * chunk;
    int local = 0;
    for (int i = 0; i < chunk; i++) {
        int idx = start + i;
        if (idx < NN) local += cnt[idx];
    }
    sums[t] = local;
    __syncthreads();
    for (int ofs = 1; ofs < 1024; ofs <<= 1) {
        int u = (t >= ofs) ? sums[t - ofs] : 0;
        __syncthreads();
        sums[t] += u;
        __syncthreads();
    }
    int base = (t == 0) ? 0 : sums[t - 1];
    for (int i = 0; i < chunk; i++) {
        int idx = start + i;
        if (idx < NN) {
            offs[idx] = base;
            cur[idx] = base;
            base += cnt[idx];
        }
    }
    if (t == 0) offs[NN] = sums[1023];
}

__global__ void k_fill(const int* __restrict__ recv, int* __restrict__ cur,
                       int* __restrict__ csr) {
    int e = blockIdx.x * blockDim.x + threadIdx.x;
    if (e < EE) {
        int r = recv[e];
        r = ((unsigned)r < NN) ? r : 0;
        int slot = atomicAdd(&cur[r], 1);
        if ((unsigned)slot < EE) csr[slot] = e;
    }
}

// ---------------- transpose W_rad2 [64][640] f32 -> w2t [640][64] bf16 -----
__global__ void k_w2t(const float* __restrict__ W_rad2,
                      unsigned short* __restrict__ w2t) {
    int i = blockIdx.x * 256 + threadIdx.x;
    if (i < 640 * 64) {
        int n = i >> 6, k = i & 63;
        w2t[i] = f2bu(W_rad2[k * 640 + n]);
    }
}

// ---- node pre: h_s/h_v, interleaved bf16 out: h4[n][c] = {s,v0,v1,v2} ----
__global__ __launch_bounds__(512) void k_pre(
    const float* __restrict__ node_feats,
    const float* __restrict__ W_up_s,
    const float* __restrict__ W_up_v,
    uint2* __restrict__ h4) {
    const int sub = threadIdx.x >> 7, d = threadIdx.x & 127;
    const int n = blockIdx.x * 4 + sub;
    __shared__ float sv[4][512];
    const float* nf = node_feats + (size_t)n * 512;
    ((float4*)sv[sub])[d] = ((const float4*)nf)[d];
    __syncthreads();
    float as = 0.f, a0 = 0.f, a1 = 0.f, a2 = 0.f;
    for (int c = 0; c < 128; c++) {
        const float wus = W_up_s[c * 128 + d];
        const float wuv = W_up_v[c * 128 + d];
        as += sv[sub][c] * wus;
        a0 += sv[sub][128 + c * 3 + 0] * wuv;
        a1 += sv[sub][128 + c * 3 + 1] * wuv;
        a2 += sv[sub][128 + c * 3 + 2] * wuv;
    }
    h4[(size_t)n * 128 + d] = make_uint2(pack2(as, a0), pack2(a1, a2));
}

// ------- MFMA edge kernel: grid-stride nodes, cooperative LDS staging ------
#define EGRID 2560
__global__ __launch_bounds__(256) void k_edge_mfma(
    const float* __restrict__ vectors,
    const float* __restrict__ radial,
    const int* __restrict__ senders,
    const float* __restrict__ W_rad1,
    const unsigned short* __restrict__ w2t,   // [640][64] bf16
    const uint2* __restrict__ h4,             // [N][128] {s,v0,v1,v2} bf16
    const int* __restrict__ offs, const int* __restrict__ csr,
    __hip_bfloat16* __restrict__ agg_g) {
    __shared__ unsigned short w1s[512];        // W_rad1 bf16 [r][u], 1 KB
    __shared__ float4 em[64];                  // {j(bits), y0,y1,y2}, 1 KB
    __shared__ float radl[64][8];              // 2 KB
    __shared__ unsigned short hid[64 * 72];    // 144 B rows, 9.2 KB
    const int tid = threadIdx.x;
    const int lane = tid & 63, wv = tid >> 6;
    const int row = lane & 15, quad = lane >> 4;
    for (int i = tid; i < 512; i += 256) w1s[i] = f2bu(W_rad1[i]);

    // --- hoist B-frags: node/edge-invariant; 20 frags = 80 VGPRs ---
    s16x8 Bf[2][5][2];
#pragma unroll
    for (int ti = 0; ti < 2; ti++) {
        const int t = 2 * wv + ti;
#pragma unroll
        for (int p = 0; p < 5; p++) {
            const unsigned short* bp =
                w2t + (size_t)(128 * p + 16 * t + row) * 64 + quad * 8;
            Bf[ti][p][0] = *(const s16x8*)(bp);
            Bf[ti][p][1] = *(const s16x8*)(bp + 32);
        }
    }

    for (int n = blockIdx.x; n < NN; n += EGRID) {
        const int start = offs[n];
        const int deg = offs[n + 1] - start;
        float acc_s[2] = {0.f, 0.f}, av0[2] = {0.f, 0.f},
              av1[2] = {0.f, 0.f}, av2[2] = {0.f, 0.f};

        for (int c0 = 0; c0 < deg; c0 += 64) {
            __syncthreads();  // protect LDS from previous chunk/node readers
            // --- stage meta (64 edges) ---
            if (tid < 64) {
                const int i = tid, gi = c0 + i;
                if (gi < deg) {
                    int e = csr[start + gi];
                    e = ((unsigned)e < EE) ? e : 0;
                    int j = senders[e];
                    j = ((unsigned)j < NN) ? j : 0;
                    const float vx = vectors[e * 3 + 0];
                    const float vy = vectors[e * 3 + 1];
                    const float vz = vectors[e * 3 + 2];
                    const float inr = 1.7320508075688772f /
                        (sqrtf(vx * vx + vy * vy + vz * vz) + 1e-9f);
                    em[i] = make_float4(__int_as_float(j), vx * inr, vy * inr, vz * inr);
                    *(float4*)&radl[i][0] = *(const float4*)(radial + (size_t)e * 8);
                    *(float4*)&radl[i][4] = *(const float4*)(radial + (size_t)e * 8 + 4);
                } else {
                    em[i] = make_float4(0.f, 0.f, 0.f, 0.f);
                    *(float4*)&radl[i][0] = make_float4(0.f, 0.f, 0.f, 0.f);
                    *(float4*)&radl[i][4] = make_float4(0.f, 0.f, 0.f, 0.f);
                }
            }
            __syncthreads();
            // --- cooperative hid: thread computes 16 units of one edge ---
            {
                const int eL = tid >> 2, u0 = (tid & 3) * 16;
                float rr[8];
#pragma unroll
                for (int r = 0; r < 8; r++) rr[r] = radl[eL][r];
                float a[16];
#pragma unroll
                for (int u = 0; u < 16; u++) a[u] = 0.f;
#pragma unroll
                for (int r = 0; r < 8; r++) {
                    const uint4 wa = *(const uint4*)&w1s[r * 64 + u0];
                    const uint4 wb = *(const uint4*)&w1s[r * 64 + u0 + 8];
                    const float f = rr[r];
                    a[0] += f * bflo(wa.x);  a[1] += f * bfhi(wa.x);
                    a[2] += f * bflo(wa.y);  a[3] += f * bfhi(wa.y);
                    a[4] += f * bflo(wa.z);  a[5] += f * bfhi(wa.z);
                    a[6] += f * bflo(wa.w);  a[7] += f * bfhi(wa.w);
                    a[8] += f * bflo(wb.x);  a[9] += f * bfhi(wb.x);
                    a[10] += f * bflo(wb.y); a[11] += f * bfhi(wb.y);
                    a[12] += f * bflo(wb.z); a[13] += f * bfhi(wb.z);
                    a[14] += f * bflo(wb.w); a[15] += f * bfhi(wb.w);
                }
                unsigned o[8];
#pragma unroll
                for (int k = 0; k < 8; k++) {
                    const float s0 = a[2 * k] / (1.f + __expf(-a[2 * k]));
                    const float s1 = a[2 * k + 1] / (1.f + __expf(-a[2 * k + 1]));
                    o[k] = pack2(s0, s1);
                }
                *(uint4*)&hid[eL * 72 + u0] = make_uint4(o[0], o[1], o[2], o[3]);
                *(uint4*)&hid[eL * 72 + u0 + 8] = make_uint4(o[4], o[5], o[6], o[7]);
            }
            __syncthreads();
            // --- group loop over this chunk (16 edges per MFMA M) ---
            const int glim = min(64, deg - c0);
            for (int g0 = 0; g0 < glim; g0 += 16) {
                const s16x8 A0 = *(const s16x8*)&hid[(g0 + row) * 72 + quad * 8];
                const s16x8 A1 = *(const s16x8*)&hid[(g0 + row) * 72 + 32 + quad * 8];
                // broadcast meta for this quad's 4 C-rows
                int jr[4]; float yr0[4], yr1[4], yr2[4];
#pragma unroll
                for (int rg = 0; rg < 4; rg++) {
                    const float4 m = em[g0 + quad * 4 + rg];
                    jr[rg] = __float_as_int(m.x);
                    yr0[rg] = m.y; yr1[rg] = m.z; yr2[rg] = m.w;
                }
#pragma unroll
                for (int ti = 0; ti < 2; ti++) {
                    const int c = 16 * (2 * wv + ti) + row;
                    float sj[4], a0r[4], a1r[4], a2r[4], dotr[4],
                          cr0[4], cr1[4], cr2[4];
#pragma unroll
                    for (int rg = 0; rg < 4; rg++) {
                        const uint2 hh = h4[(size_t)jr[rg] * 128 + c];
                        const float s_ = bflo(hh.x), a0 = bfhi(hh.x);
                        const float a1 = bflo(hh.y), a2 = bfhi(hh.y);
                        sj[rg] = s_; a0r[rg] = a0; a1r[rg] = a1; a2r[rg] = a2;
                        dotr[rg] = a0 * yr0[rg] + a1 * yr1[rg] + a2 * yr2[rg];
                        cr0[rg] = a1 * yr2[rg] - a2 * yr1[rg];
                        cr1[rg] = a2 * yr0[rg] - a0 * yr2[rg];
                        cr2[rg] = a0 * yr1[rg] - a1 * yr0[rg];
                    }
#pragma unroll
                    for (int p = 0; p < 5; p++) {
                        f32x4 z = {0.f, 0.f, 0.f, 0.f};
                        z = __builtin_amdgcn_mfma_f32_16x16x32_bf16(A0, Bf[ti][p][0], z, 0, 0, 0);
                        z = __builtin_amdgcn_mfma_f32_16x16x32_bf16(A1, Bf[ti][p][1], z, 0, 0, 0);
#pragma unroll
                        for (int rg = 0; rg < 4; rg++) {
                            const float w = z[rg];
                            if (p == 0) {
                                acc_s[ti] += w * sj[rg];
                            } else if (p == 1) {
                                const float ws = w * sj[rg];
                                av0[ti] += ws * yr0[rg];
                                av1[ti] += ws * yr1[rg];
                                av2[ti] += ws * yr2[rg];
                            } else if (p == 2) {
                                av0[ti] += w * a0r[rg];
                                av1[ti] += w * a1r[rg];
                                av2[ti] += w * a2r[rg];
                            } else if (p == 3) {
                                acc_s[ti] += w * dotr[rg];
                            } else {
                                av0[ti] += w * cr0[rg];
                                av1[ti] += w * cr1[rg];
                                av2[ti] += w * cr2[rg];
                            }
                        }
                    }
                }
            }
        }
        // --- cross-quad reduction + store ---
#pragma unroll
        for (int ti = 0; ti < 2; ti++) {
            acc_s[ti] += __shfl_xor(acc_s[ti], 16); acc_s[ti] += __shfl_xor(acc_s[ti], 32);
            av0[ti] += __shfl_xor(av0[ti], 16);     av0[ti] += __shfl_xor(av0[ti], 32);
            av1[ti] += __shfl_xor(av1[ti], 16);     av1[ti] += __shfl_xor(av1[ti], 32);
            av2[ti] += __shfl_xor(av2[ti], 16);     av2[ti] += __shfl_xor(av2[ti], 32);
        }
        if (lane < 16) {
            unsigned short* og = (unsigned short*)agg_g + (size_t)n * 512;
#pragma unroll
            for (int ti = 0; ti < 2; ti++) {
                const int c = 16 * (2 * wv + ti) + lane;
                og[c] = f2bu(acc_s[ti]);
                og[128 + 3 * c + 0] = f2bu(av0[ti]);
                og[128 + 3 * c + 1] = f2bu(av1[ti]);
                og[128 + 3 * c + 2] = f2bu(av2[ti]);
            }
        }
    }
}

// ---------------- node post: down/prod/lin/skip/readout ----------------
__global__ __launch_bounds__(512) void k_post(
    const float* __restrict__ node_feats,
    const int* __restrict__ specie,
    const __hip_bfloat16* __restrict__ agg_g,
    const float* __restrict__ W_down_s,
    const float* __restrict__ W_down_v,
    const float* __restrict__ W_skip_s,
    const float* __restrict__ W_skip_v,
    const float* __restrict__ W_prod_s,
    const float* __restrict__ W_prod_v,
    const float* __restrict__ W_lin_s,
    const float* __restrict__ W_lin_v,
    const float* __restrict__ W_ro,
    float* __restrict__ d_out) {
    const int sub = threadIdx.x >> 7, d = threadIdx.x & 127;
    const int n = blockIdx.x * 4 + sub;
    __shared__ float sv[4][512];
    __shared__ float ag[4][512];
    __shared__ float pl[4][512];
    __shared__ float red[4][2];
    const float* nf = node_feats + (size_t)n * 512;
    const __hip_bfloat16* agp = agg_g + (size_t)n * 512;
    ((float4*)sv[sub])[d] = ((const float4*)nf)[d];
    for (int i = d; i < 512; i += 128) ag[sub][i] = b2f(agp[i]);
    __syncthreads();
    int spec = specie[n];
    spec = ((unsigned)spec < 10) ? spec : 0;
    const float* Wss = W_skip_s + (size_t)spec * 16384;
    const float* Wsv = W_skip_v + (size_t)spec * 16384;
    float scs = 0, scv0 = 0, scv1 = 0, scv2 = 0, fs = 0, fv0 = 0, fv1 = 0, fv2 = 0;
    for (int c = 0; c < 128; c++) {
        const float s_c = sv[sub][c];
        const float v0 = sv[sub][128 + c * 3 + 0];
        const float v1 = sv[sub][128 + c * 3 + 1];
        const float v2 = sv[sub][128 + c * 3 + 2];
        const float a_c = ag[sub][c];
        const float a0 = ag[sub][128 + c * 3 + 0];
        const float a1 = ag[sub][128 + c * 3 + 1];
        const float a2 = ag[sub][128 + c * 3 + 2];
        const float wss = Wss[c * 128 + d];
        const float wsv = Wsv[c * 128 + d];
        const float wds = W_down_s[c * 128 + d];
        const float wdv = W_down_v[c * 128 + d];
        scs += s_c * wss;
        scv0 += v0 * wsv; scv1 += v1 * wsv; scv2 += v2 * wsv;
        fs += a_c * wds;
        fv0 += a0 * wdv; fv1 += a1 * wdv; fv2 += a2 * wdv;
    }
    fs *= FEPS; fv0 *= FEPS; fv1 *= FEPS; fv2 *= FEPS;
    const float ps = fs * W_prod_s[spec * 384 + d]
                   + fs * fs * W_prod_s[spec * 384 + 128 + d]
                   + (fv0 * fv0 + fv1 * fv1 + fv2 * fv2) * W_prod_s[spec * 384 + 256 + d];
    const float pw0 = W_prod_v[spec * 256 + d];
    const float pw1 = W_prod_v[spec * 256 + 128 + d];
    const float pv0 = fv0 * pw0 + fs * fv0 * pw1;
    const float pv1 = fv1 * pw0 + fs * fv1 * pw1;
    const float pv2 = fv2 * pw0 + fs * fv2 * pw1;
    pl[sub][d] = ps;
    pl[sub][128 + d * 3 + 0] = pv0;
    pl[sub][128 + d * 3 + 1] = pv1;
    pl[sub][128 + d * 3 + 2] = pv2;
    __syncthreads();
    float outs = scs, ov0 = scv0, ov1 = scv1, ov2 = scv2;
    for (int c = 0; c < 128; c++) {
        const float wls = W_lin_s[c * 128 + d];
        const float wlv = W_lin_v[c * 128 + d];
        outs += pl[sub][c] * wls;
        ov0 += pl[sub][128 + c * 3 + 0] * wlv;
        ov1 += pl[sub][128 + c * 3 + 1] * wlv;
        ov2 += pl[sub][128 + c * 3 + 2] * wlv;
    }
    float* o1 = d_out + NN + (size_t)n * 512;
    o1[d] = outs;
    o1[128 + d * 3 + 0] = ov0;
    o1[128 + d * 3 + 1] = ov1;
    o1[128 + d * 3 + 2] = ov2;
    float r = outs * W_ro[d];
#pragma unroll
    for (int o = 32; o > 0; o >>= 1) r += __shfl_down(r, o);
    const int lane = threadIdx.x & 63;
    const int wv_in_sub = (threadIdx.x >> 6) & 1;
    if (lane == 0) red[sub][wv_in_sub] = r;
    __syncthreads();
    if (d == 0) d_out[n] = red[sub][0] + red[sub][1];
}

extern "C" void kernel_launch(void* const* d_in, const int* in_sizes, int n_in,
                              void* d_out, int out_size, void* d_ws, size_t ws_size,
                              hipStream_t stream) {
    const float* vectors    = (const float*)d_in[0];
    const float* node_feats = (const float*)d_in[1];
    const int*   specie     = (const int*)d_in[2];
    const float* radial     = (const float*)d_in[3];
    const int*   senders    = (const int*)d_in[4];
    const int*   receivers  = (const int*)d_in[5];
    const float* W_up_s     = (const float*)d_in[6];
    const float* W_up_v     = (const float*)d_in[7];
    const float* W_rad1     = (const float*)d_in[8];
    const float* W_rad2     = (const float*)d_in[9];
    const float* W_down_s   = (const float*)d_in[10];
    const float* W_down_v   = (const float*)d_in[11];
    const float* W_skip_s   = (const float*)d_in[12];
    const float* W_skip_v   = (const float*)d_in[13];
    const float* W_prod_s   = (const float*)d_in[14];
    const float* W_prod_v   = (const float*)d_in[15];
    const float* W_lin_s    = (const float*)d_in[16];
    const float* W_lin_v    = (const float*)d_in[17];
    const float* W_ro       = (const float*)d_in[18];
    float* out = (float*)d_out;

    // workspace carve (~22.2 MB): CSR first, interleaved h4, bf16 agg, w2t
    char* w = (char*)d_ws;
    auto align256 = [](size_t x) { return (x + 255) & ~(size_t)255; };
    int* cnt  = (int*)w;              w += align256((size_t)NN * 4);
    int* offs = (int*)w;              w += align256((size_t)(NN + 1) * 4);
    int* cur  = (int*)w;              w += align256((size_t)NN * 4);
    int* csr  = (int*)w;              w += align256((size_t)EE * 4);
    uint2* h4 = (uint2*)w;            w += align256((size_t)NN * 128 * 8);
    __hip_bfloat16* agg_g = (__hip_bfloat16*)w;  w += align256((size_t)NN * 512 * 2);
    unsigned short* w2t   = (unsigned short*)w;  // 640*64*2 = 80 KB

    hipMemsetAsync(cnt, 0, NN * sizeof(int), stream);
    k_hist<<<(EE + 255) / 256, 256, 0, stream>>>(receivers, cnt);
    k_scan<<<1, 1024, 0, stream>>>(cnt, offs, cur);
    k_fill<<<(EE + 255) / 256, 256, 0, stream>>>(receivers, cur, csr);
    k_w2t<<<160, 256, 0, stream>>>(W_rad2, w2t);
    k_pre<<<NN / 4, 512, 0, stream>>>(node_feats, W_up_s, W_up_v, h4);
    k_edge_mfma<<<EGRID, 256, 0, stream>>>(vectors, radial, senders, W_rad1,
                                           w2t, h4, offs, csr, agg_g);
    k_post<<<NN / 4, 512, 0, stream>>>(node_feats, specie, agg_g,
                                       W_down_s, W_down_v, W_skip_s, W_skip_v,
                                       W_prod_s, W_prod_v, W_lin_s, W_lin_v,
                                       W_ro, out);
}

// Round 8
// 597.646 us; speedup vs baseline: 2.1852x; 1.0392x over previous
//
#include <hip/hip_runtime.h>
#include <hip/hip_bf16.h>

// MACE layer forward, MI355X (gfx950). f32 I/O, bf16 internals.
// Round 8: MFMA-ize pre/post. Non-edge time was flat ~330us across R4-R7:
// k_pre/k_post are 5.2 GFLOP of 128x128 matmuls running on the f32 VALU.
// - k_wt: all 26 weight mats (up/down/lin/skip[10]x2) -> bf16 [d][c] tables
// - k_spec: species-bucket perm + 16-node species-uniform tile descriptors
// - k_pre_mfma: [s,v0..2]@W_up via 16x16x32 MFMA -> h4
// - k_post_mfma: down+skip GEMMs -> prod elementwise -> P via LDS -> lin
//   GEMM + skip add -> outputs + readout (LDS atomics)
// - k_edge unchanged except agg stored planar [n][4][128] bf16.

#define NN 10000
#define EE 320000
#define FEPS 0.17677669529663687f

typedef __attribute__((ext_vector_type(4))) float f32x4;
typedef __attribute__((ext_vector_type(8))) short s16x8;

__device__ __forceinline__ float bflo(unsigned u) { return __uint_as_float(u << 16); }
__device__ __forceinline__ float bfhi(unsigned u) { return __uint_as_float(u & 0xffff0000u); }
__device__ __forceinline__ unsigned short f2bu(float f) {
    unsigned u = __float_as_uint(f);
    return (unsigned short)((u + 0x7FFFu + ((u >> 16) & 1u)) >> 16);
}
__device__ __forceinline__ unsigned pack2(float a, float b) {
    return (unsigned)f2bu(a) | ((unsigned)f2bu(b) << 16);
}
__device__ __forceinline__ s16x8 pack8(float4 a, float4 b) {
    union { s16x8 v; unsigned short u[8]; } r;
    r.u[0] = f2bu(a.x); r.u[1] = f2bu(a.y); r.u[2] = f2bu(a.z); r.u[3] = f2bu(a.w);
    r.u[4] = f2bu(b.x); r.u[5] = f2bu(b.y); r.u[6] = f2bu(b.z); r.u[7] = f2bu(b.w);
    return r.v;
}

// ---------------- CSR build ----------------
__global__ void k_hist(const int* __restrict__ recv, int* __restrict__ cnt) {
    int e = blockIdx.x * blockDim.x + threadIdx.x;
    if (e < EE) {
        int r = recv[e];
        r = ((unsigned)r < NN) ? r : 0;
        atomicAdd(&cnt[r], 1);
    }
}

__global__ void k_scan(const int* __restrict__ cnt, int* __restrict__ offs,
                       int* __restrict__ cur) {
    __shared__ int sums[1024];
    const int t = threadIdx.x;
    const int chunk = (NN + 1023) / 1024;  // 10
    const int start = t * chunk;
    int local = 0;
    for (int i = 0; i < chunk; i++) {
        int idx = start + i;
        if (idx < NN) local += cnt[idx];
    }
    sums[t] = local;
    __syncthreads();
    for (int ofs = 1; ofs < 1024; ofs <<= 1) {
        int u = (t >= ofs) ? sums[t - ofs] : 0;
        __syncthreads();
        sums[t] += u;
        __syncthreads();
    }
    int base = (t == 0) ? 0 : sums[t - 1];
    for (int i = 0; i < chunk; i++) {
        int idx = start + i;
        if (idx < NN) {
            offs[idx] = base;
            cur[idx] = base;
            base += cnt[idx];
        }
    }
    if (t == 0) offs[NN] = sums[1023];
}

__global__ void k_fill(const int* __restrict__ recv, int* __restrict__ cur,
                       int* __restrict__ csr) {
    int e = blockIdx.x * blockDim.x + threadIdx.x;
    if (e < EE) {
        int r = recv[e];
        r = ((unsigned)r < NN) ? r : 0;
        int slot = atomicAdd(&cur[r], 1);
        if ((unsigned)slot < EE) csr[slot] = e;
    }
}

// ------- species buckets: perm + 16-node species-uniform tiles -------
__global__ void k_spec(const int* __restrict__ specie, int* __restrict__ perm,
                       int2* __restrict__ tiles, int* __restrict__ ntiles) {
    __shared__ int hcnt[10], hcur[10];
    const int tid = threadIdx.x;
    if (tid < 10) hcnt[tid] = 0;
    __syncthreads();
    for (int n = tid; n < NN; n += 256) {
        int s = specie[n];
        s = ((unsigned)s < 10) ? s : 0;
        atomicAdd(&hcnt[s], 1);
    }
    __syncthreads();
    if (tid == 0) {
        int run = 0, tc = 0;
        for (int sp = 0; sp < 10; sp++) {
            hcur[sp] = run;
            const int c = hcnt[sp];
            for (int b = 0; b < c; b += 16)
                tiles[tc++] = make_int2(run + b, (sp << 8) | min(16, c - b));
            run += c;
        }
        *ntiles = tc;
    }
    __syncthreads();
    for (int n = tid; n < NN; n += 256) {
        int s = specie[n];
        s = ((unsigned)s < 10) ? s : 0;
        int slot = atomicAdd(&hcur[s], 1);
        if ((unsigned)slot < NN) perm[slot] = n;
    }
}

// ------- transpose+convert 26 weight mats -> bf16 [d][c] tables -------
// order: 0 up_s, 1 up_v, 2 down_s, 3 down_v, 4 lin_s, 5 lin_v,
//        6..15 skip_s[sp], 16..25 skip_v[sp]
__global__ void k_wt(const float* __restrict__ Wus, const float* __restrict__ Wuv,
                     const float* __restrict__ Wds, const float* __restrict__ Wdv,
                     const float* __restrict__ Wls, const float* __restrict__ Wlv,
                     const float* __restrict__ Wss, const float* __restrict__ Wsv,
                     unsigned short* __restrict__ T) {
    int idx = blockIdx.x * 256 + threadIdx.x;
    if (idx >= 26 * 16384) return;
    const int m = idx >> 14, p = idx & 16383, d = p >> 7, c = p & 127;
    const float* src;
    if (m == 0) src = Wus; else if (m == 1) src = Wuv;
    else if (m == 2) src = Wds; else if (m == 3) src = Wdv;
    else if (m == 4) src = Wls; else if (m == 5) src = Wlv;
    else if (m < 16) src = Wss + (size_t)(m - 6) * 16384;
    else src = Wsv + (size_t)(m - 16) * 16384;
    T[(size_t)m * 16384 + d * 128 + c] = f2bu(src[c * 128 + d]);
}

// ---------------- transpose W_rad2 [64][640] f32 -> w2t [640][64] bf16 -----
__global__ void k_w2t(const float* __restrict__ W_rad2,
                      unsigned short* __restrict__ w2t) {
    int i = blockIdx.x * 256 + threadIdx.x;
    if (i < 640 * 64) {
        int n = i >> 6, k = i & 63;
        w2t[i] = f2bu(W_rad2[k * 640 + n]);
    }
}

// ---------------- pre: h = [s,v]@W_up via MFMA -> h4 interleaved ----------
__global__ __launch_bounds__(256) void k_pre_mfma(
    const float* __restrict__ nf,
    const unsigned short* __restrict__ Tw,
    uint2* __restrict__ h4) {
    const int tile = blockIdx.x;  // 625 tiles of 16 nodes
    const int tid = threadIdx.x;
    const int lane = tid & 63, wv = tid >> 6;
    const int col = lane & 15, quad = lane >> 4;
    const int mN = tile * 16 + col;
    const float* rp = nf + (size_t)mN * 512;
    // A-frags (m=col): 4 mats x 4 k-tiles
    s16x8 Af[4][4];
#pragma unroll
    for (int kt = 0; kt < 4; kt++) {
        const int ko = kt * 32 + quad * 8;
        const float4 fa = *(const float4*)(rp + ko);
        const float4 fb = *(const float4*)(rp + ko + 4);
        Af[0][kt] = pack8(fa, fb);
#pragma unroll
        for (int i = 0; i < 3; i++) {
            union { s16x8 v; unsigned short u[8]; } A;
#pragma unroll
            for (int j = 0; j < 8; j++) A.u[j] = f2bu(rp[128 + 3 * (ko + j) + i]);
            Af[1 + i][kt] = A.v;
        }
    }
    const unsigned short* Ts = Tw;
    const unsigned short* Tv = Tw + 16384;
#pragma unroll
    for (int nt = 0; nt < 2; nt++) {
        const int n0 = 32 * wv + 16 * nt;
        const int d = n0 + col;
        f32x4 C[4];
#pragma unroll
        for (int m = 0; m < 4; m++) C[m] = (f32x4){0.f, 0.f, 0.f, 0.f};
#pragma unroll
        for (int kt = 0; kt < 4; kt++) {
            const int ko = kt * 32 + quad * 8;
            const s16x8 Bs = *(const s16x8*)&Ts[(size_t)d * 128 + ko];
            const s16x8 Bv = *(const s16x8*)&Tv[(size_t)d * 128 + ko];
            C[0] = __builtin_amdgcn_mfma_f32_16x16x32_bf16(Af[0][kt], Bs, C[0], 0, 0, 0);
#pragma unroll
            for (int i = 0; i < 3; i++)
                C[1 + i] = __builtin_amdgcn_mfma_f32_16x16x32_bf16(Af[1 + i][kt], Bv, C[1 + i], 0, 0, 0);
        }
#pragma unroll
        for (int reg = 0; reg < 4; reg++) {
            const int node = tile * 16 + quad * 4 + reg;
            h4[(size_t)node * 128 + d] =
                make_uint2(pack2(C[0][reg], C[1][reg]), pack2(C[2][reg], C[3][reg]));
        }
    }
}

// ------- MFMA edge kernel: grid-stride nodes, cooperative LDS staging ------
#define EGRID 2560
__global__ __launch_bounds__(256) void k_edge_mfma(
    const float* __restrict__ vectors,
    const float* __restrict__ radial,
    const int* __restrict__ senders,
    const float* __restrict__ W_rad1,
    const unsigned short* __restrict__ w2t,   // [640][64] bf16
    const uint2* __restrict__ h4,             // [N][128] {s,v0,v1,v2} bf16
    const int* __restrict__ offs, const int* __restrict__ csr,
    unsigned short* __restrict__ aggb) {      // [N][4][128] bf16 planar
    __shared__ unsigned short w1s[512];
    __shared__ float4 em[64];
    __shared__ float radl[64][8];
    __shared__ unsigned short hid[64 * 72];
    const int tid = threadIdx.x;
    const int lane = tid & 63, wv = tid >> 6;
    const int row = lane & 15, quad = lane >> 4;
    for (int i = tid; i < 512; i += 256) w1s[i] = f2bu(W_rad1[i]);

    s16x8 Bf[2][5][2];
#pragma unroll
    for (int ti = 0; ti < 2; ti++) {
        const int t = 2 * wv + ti;
#pragma unroll
        for (int p = 0; p < 5; p++) {
            const unsigned short* bp =
                w2t + (size_t)(128 * p + 16 * t + row) * 64 + quad * 8;
            Bf[ti][p][0] = *(const s16x8*)(bp);
            Bf[ti][p][1] = *(const s16x8*)(bp + 32);
        }
    }

    for (int n = blockIdx.x; n < NN; n += EGRID) {
        const int start = offs[n];
        const int deg = offs[n + 1] - start;
        float acc_s[2] = {0.f, 0.f}, av0[2] = {0.f, 0.f},
              av1[2] = {0.f, 0.f}, av2[2] = {0.f, 0.f};

        for (int c0 = 0; c0 < deg; c0 += 64) {
            __syncthreads();
            if (tid < 64) {
                const int i = tid, gi = c0 + i;
                if (gi < deg) {
                    int e = csr[start + gi];
                    e = ((unsigned)e < EE) ? e : 0;
                    int j = senders[e];
                    j = ((unsigned)j < NN) ? j : 0;
                    const float vx = vectors[e * 3 + 0];
                    const float vy = vectors[e * 3 + 1];
                    const float vz = vectors[e * 3 + 2];
                    const float inr = 1.7320508075688772f /
                        (sqrtf(vx * vx + vy * vy + vz * vz) + 1e-9f);
                    em[i] = make_float4(__int_as_float(j), vx * inr, vy * inr, vz * inr);
                    *(float4*)&radl[i][0] = *(const float4*)(radial + (size_t)e * 8);
                    *(float4*)&radl[i][4] = *(const float4*)(radial + (size_t)e * 8 + 4);
                } else {
                    em[i] = make_float4(0.f, 0.f, 0.f, 0.f);
                    *(float4*)&radl[i][0] = make_float4(0.f, 0.f, 0.f, 0.f);
                    *(float4*)&radl[i][4] = make_float4(0.f, 0.f, 0.f, 0.f);
                }
            }
            __syncthreads();
            {
                const int eL = tid >> 2, u0 = (tid & 3) * 16;
                float rr[8];
#pragma unroll
                for (int r = 0; r < 8; r++) rr[r] = radl[eL][r];
                float a[16];
#pragma unroll
                for (int u = 0; u < 16; u++) a[u] = 0.f;
#pragma unroll
                for (int r = 0; r < 8; r++) {
                    const uint4 wa = *(const uint4*)&w1s[r * 64 + u0];
                    const uint4 wb = *(const uint4*)&w1s[r * 64 + u0 + 8];
                    const float f = rr[r];
                    a[0] += f * bflo(wa.x);  a[1] += f * bfhi(wa.x);
                    a[2] += f * bflo(wa.y);  a[3] += f * bfhi(wa.y);
                    a[4] += f * bflo(wa.z);  a[5] += f * bfhi(wa.z);
                    a[6] += f * bflo(wa.w);  a[7] += f * bfhi(wa.w);
                    a[8] += f * bflo(wb.x);  a[9] += f * bfhi(wb.x);
                    a[10] += f * bflo(wb.y); a[11] += f * bfhi(wb.y);
                    a[12] += f * bflo(wb.z); a[13] += f * bfhi(wb.z);
                    a[14] += f * bflo(wb.w); a[15] += f * bfhi(wb.w);
                }
                unsigned o[8];
#pragma unroll
                for (int k = 0; k < 8; k++) {
                    const float s0 = a[2 * k] / (1.f + __expf(-a[2 * k]));
                    const float s1 = a[2 * k + 1] / (1.f + __expf(-a[2 * k + 1]));
                    o[k] = pack2(s0, s1);
                }
                *(uint4*)&hid[eL * 72 + u0] = make_uint4(o[0], o[1], o[2], o[3]);
                *(uint4*)&hid[eL * 72 + u0 + 8] = make_uint4(o[4], o[5], o[6], o[7]);
            }
            __syncthreads();
            const int glim = min(64, deg - c0);
            for (int g0 = 0; g0 < glim; g0 += 16) {
                const s16x8 A0 = *(const s16x8*)&hid[(g0 + row) * 72 + quad * 8];
                const s16x8 A1 = *(const s16x8*)&hid[(g0 + row) * 72 + 32 + quad * 8];
                int jr[4]; float yr0[4], yr1[4], yr2[4];
#pragma unroll
                for (int rg = 0; rg < 4; rg++) {
                    const float4 m = em[g0 + quad * 4 + rg];
                    jr[rg] = __float_as_int(m.x);
                    yr0[rg] = m.y; yr1[rg] = m.z; yr2[rg] = m.w;
                }
#pragma unroll
                for (int ti = 0; ti < 2; ti++) {
                    const int c = 16 * (2 * wv + ti) + row;
                    float sj[4], a0r[4], a1r[4], a2r[4], dotr[4],
                          cr0[4], cr1[4], cr2[4];
#pragma unroll
                    for (int rg = 0; rg < 4; rg++) {
                        const uint2 hh = h4[(size_t)jr[rg] * 128 + c];
                        const float s_ = bflo(hh.x), a0 = bfhi(hh.x);
                        const float a1 = bflo(hh.y), a2 = bfhi(hh.y);
                        sj[rg] = s_; a0r[rg] = a0; a1r[rg] = a1; a2r[rg] = a2;
                        dotr[rg] = a0 * yr0[rg] + a1 * yr1[rg] + a2 * yr2[rg];
                        cr0[rg] = a1 * yr2[rg] - a2 * yr1[rg];
                        cr1[rg] = a2 * yr0[rg] - a0 * yr2[rg];
                        cr2[rg] = a0 * yr1[rg] - a1 * yr0[rg];
                    }
#pragma unroll
                    for (int p = 0; p < 5; p++) {
                        f32x4 z = {0.f, 0.f, 0.f, 0.f};
                        z = __builtin_amdgcn_mfma_f32_16x16x32_bf16(A0, Bf[ti][p][0], z, 0, 0, 0);
                        z = __builtin_amdgcn_mfma_f32_16x16x32_bf16(A1, Bf[ti][p][1], z, 0, 0, 0);
#pragma unroll
                        for (int rg = 0; rg < 4; rg++) {
                            const float w = z[rg];
                            if (p == 0) {
                                acc_s[ti] += w * sj[rg];
                            } else if (p == 1) {
                                const float ws = w * sj[rg];
                                av0[ti] += ws * yr0[rg];
                                av1[ti] += ws * yr1[rg];
                                av2[ti] += ws * yr2[rg];
                            } else if (p == 2) {
                                av0[ti] += w * a0r[rg];
                                av1[ti] += w * a1r[rg];
                                av2[ti] += w * a2r[rg];
                            } else if (p == 3) {
                                acc_s[ti] += w * dotr[rg];
                            } else {
                                av0[ti] += w * cr0[rg];
                                av1[ti] += w * cr1[rg];
                                av2[ti] += w * cr2[rg];
                            }
                        }
                    }
                }
            }
        }
#pragma unroll
        for (int ti = 0; ti < 2; ti++) {
            acc_s[ti] += __shfl_xor(acc_s[ti], 16); acc_s[ti] += __shfl_xor(acc_s[ti], 32);
            av0[ti] += __shfl_xor(av0[ti], 16);     av0[ti] += __shfl_xor(av0[ti], 32);
            av1[ti] += __shfl_xor(av1[ti], 16);     av1[ti] += __shfl_xor(av1[ti], 32);
            av2[ti] += __shfl_xor(av2[ti], 16);     av2[ti] += __shfl_xor(av2[ti], 32);
        }
        if (lane < 16) {
            unsigned short* og = aggb + (size_t)n * 512;
#pragma unroll
            for (int ti = 0; ti < 2; ti++) {
                const int c = 16 * (2 * wv + ti) + lane;
                og[c] = f2bu(acc_s[ti]);
                og[128 + c] = f2bu(av0[ti]);
                og[256 + c] = f2bu(av1[ti]);
                og[384 + c] = f2bu(av2[ti]);
            }
        }
    }
}

// -------- post: down+skip GEMM -> prod -> P via LDS -> lin GEMM + out ------
__global__ __launch_bounds__(256) void k_post_mfma(
    const float* __restrict__ nf,
    const unsigned short* __restrict__ aggb,
    const int* __restrict__ perm,
    const int2* __restrict__ tiles,
    const int* __restrict__ ntiles,
    const unsigned short* __restrict__ Tw,
    const float* __restrict__ Wps,
    const float* __restrict__ Wpv,
    const float* __restrict__ Wro,
    float* __restrict__ dout) {
    const int tile = blockIdx.x;
    if (tile >= *ntiles) return;
    const int2 td = tiles[tile];
    const int base = td.x, sp = td.y >> 8, cnt = td.y & 255;
    __shared__ int nodesl[16];
    __shared__ float rol[16];
    __shared__ unsigned short Pl[4][16][128];  // 16 KB
    const int tid = threadIdx.x;
    if (tid < 16) {
        nodesl[tid] = perm[base + ((tid < cnt) ? tid : 0)];
        rol[tid] = 0.f;
    }
    __syncthreads();
    const int lane = tid & 63, wv = tid >> 6;
    const int col = lane & 15, quad = lane >> 4;
    const int aN = nodesl[col];
    const unsigned short* Tds = Tw + (size_t)2 * 16384;
    const unsigned short* Tdv = Tw + (size_t)3 * 16384;
    const unsigned short* Tls = Tw + (size_t)4 * 16384;
    const unsigned short* Tlv = Tw + (size_t)5 * 16384;
    const unsigned short* Tss = Tw + (size_t)(6 + sp) * 16384;
    const unsigned short* Tsv = Tw + (size_t)(16 + sp) * 16384;
    const float* rp = nf + (size_t)aN * 512;
    f32x4 SC[2][4];
#pragma unroll
    for (int nt = 0; nt < 2; nt++) {
        const int n0 = 32 * wv + 16 * nt;
        const int d = n0 + col;
        // --- F = agg @ W_down ---
        f32x4 CF[4];
#pragma unroll
        for (int m = 0; m < 4; m++) CF[m] = (f32x4){0.f, 0.f, 0.f, 0.f};
#pragma unroll
        for (int kt = 0; kt < 4; kt++) {
            const int ko = kt * 32 + quad * 8;
            const s16x8 Bs = *(const s16x8*)&Tds[(size_t)d * 128 + ko];
            const s16x8 Bv = *(const s16x8*)&Tdv[(size_t)d * 128 + ko];
#pragma unroll
            for (int m = 0; m < 4; m++) {
                const s16x8 A = *(const s16x8*)&aggb[(size_t)aN * 512 + m * 128 + ko];
                CF[m] = __builtin_amdgcn_mfma_f32_16x16x32_bf16(A, m ? Bv : Bs, CF[m], 0, 0, 0);
            }
        }
        // --- elementwise prod -> P (LDS, bf16) ---
        const float wps0 = Wps[sp * 384 + d];
        const float wps1 = Wps[sp * 384 + 128 + d];
        const float wps2 = Wps[sp * 384 + 256 + d];
        const float wpv0 = Wpv[sp * 256 + d];
        const float wpv1 = Wpv[sp * 256 + 128 + d];
#pragma unroll
        for (int reg = 0; reg < 4; reg++) {
            const float fs = CF[0][reg] * FEPS;
            const float f0 = CF[1][reg] * FEPS;
            const float f1 = CF[2][reg] * FEPS;
            const float f2 = CF[3][reg] * FEPS;
            const float ps = fs * wps0 + fs * fs * wps1 + (f0 * f0 + f1 * f1 + f2 * f2) * wps2;
            const float pb = wpv0 + fs * wpv1;
            const int r = quad * 4 + reg;
            Pl[0][r][d] = f2bu(ps);
            Pl[1][r][d] = f2bu(f0 * pb);
            Pl[2][r][d] = f2bu(f1 * pb);
            Pl[3][r][d] = f2bu(f2 * pb);
        }
        // --- SC = [s,v] @ W_skip[sp] ---
        f32x4 CS[4];
#pragma unroll
        for (int m = 0; m < 4; m++) CS[m] = (f32x4){0.f, 0.f, 0.f, 0.f};
#pragma unroll
        for (int kt = 0; kt < 4; kt++) {
            const int ko = kt * 32 + quad * 8;
            const s16x8 Bss = *(const s16x8*)&Tss[(size_t)d * 128 + ko];
            const s16x8 Bsv = *(const s16x8*)&Tsv[(size_t)d * 128 + ko];
            const float4 fa = *(const float4*)(rp + ko);
            const float4 fb = *(const float4*)(rp + ko + 4);
            CS[0] = __builtin_amdgcn_mfma_f32_16x16x32_bf16(pack8(fa, fb), Bss, CS[0], 0, 0, 0);
#pragma unroll
            for (int i = 0; i < 3; i++) {
                union { s16x8 v; unsigned short u[8]; } A;
#pragma unroll
                for (int j = 0; j < 8; j++) A.u[j] = f2bu(rp[128 + 3 * (ko + j) + i]);
                CS[1 + i] = __builtin_amdgcn_mfma_f32_16x16x32_bf16(A.v, Bsv, CS[1 + i], 0, 0, 0);
            }
        }
#pragma unroll
        for (int m = 0; m < 4; m++) SC[nt][m] = CS[m];
    }
    __syncthreads();  // Pl complete across all waves
#pragma unroll
    for (int nt = 0; nt < 2; nt++) {
        const int n0 = 32 * wv + 16 * nt;
        const int d = n0 + col;
        f32x4 CL[4];
#pragma unroll
        for (int m = 0; m < 4; m++) CL[m] = (f32x4){0.f, 0.f, 0.f, 0.f};
#pragma unroll
        for (int kt = 0; kt < 4; kt++) {
            const int ko = kt * 32 + quad * 8;
            const s16x8 Bls = *(const s16x8*)&Tls[(size_t)d * 128 + ko];
            const s16x8 Blv = *(const s16x8*)&Tlv[(size_t)d * 128 + ko];
#pragma unroll
            for (int m = 0; m < 4; m++) {
                const s16x8 A = *(const s16x8*)&Pl[m][col][ko];
                CL[m] = __builtin_amdgcn_mfma_f32_16x16x32_bf16(A, m ? Blv : Bls, CL[m], 0, 0, 0);
            }
        }
        const float wro = Wro[d];
#pragma unroll
        for (int reg = 0; reg < 4; reg++) {
            const int r = quad * 4 + reg;
            if (r < cnt) {
                const int node = nodesl[r];
                const float outs = CL[0][reg] + SC[nt][0][reg];
                const float o0 = CL[1][reg] + SC[nt][1][reg];
                const float o1 = CL[2][reg] + SC[nt][2][reg];
                const float o2 = CL[3][reg] + SC[nt][3][reg];
                float* o = dout + NN + (size_t)node * 512;
                o[d] = outs;
                o[128 + 3 * d + 0] = o0;
                o[128 + 3 * d + 1] = o1;
                o[128 + 3 * d + 2] = o2;
                atomicAdd(&rol[r], outs * wro);
            }
        }
    }
    __syncthreads();
    if (tid < 16 && tid < cnt) dout[nodesl[tid]] = rol[tid];
}

extern "C" void kernel_launch(void* const* d_in, const int* in_sizes, int n_in,
                              void* d_out, int out_size, void* d_ws, size_t ws_size,
                              hipStream_t stream) {
    const float* vectors    = (const float*)d_in[0];
    const float* node_feats = (const float*)d_in[1];
    const int*   specie     = (const int*)d_in[2];
    const float* radial     = (const float*)d_in[3];
    const int*   senders    = (const int*)d_in[4];
    const int*   receivers  = (const int*)d_in[5];
    const float* W_up_s     = (const float*)d_in[6];
    const float* W_up_v     = (const float*)d_in[7];
    const float* W_rad1     = (const float*)d_in[8];
    const float* W_rad2     = (const float*)d_in[9];
    const float* W_down_s   = (const float*)d_in[10];
    const float* W_down_v   = (const float*)d_in[11];
    const float* W_skip_s   = (const float*)d_in[12];
    const float* W_skip_v   = (const float*)d_in[13];
    const float* W_prod_s   = (const float*)d_in[14];
    const float* W_prod_v   = (const float*)d_in[15];
    const float* W_lin_s    = (const float*)d_in[16];
    const float* W_lin_v    = (const float*)d_in[17];
    const float* W_ro       = (const float*)d_in[18];
    float* out = (float*)d_out;

    // workspace carve (~23 MB)
    char* w = (char*)d_ws;
    auto align256 = [](size_t x) { return (x + 255) & ~(size_t)255; };
    int* cnt  = (int*)w;              w += align256((size_t)NN * 4);
    int* offs = (int*)w;              w += align256((size_t)(NN + 1) * 4);
    int* cur  = (int*)w;              w += align256((size_t)NN * 4);
    int* csr  = (int*)w;              w += align256((size_t)EE * 4);
    uint2* h4 = (uint2*)w;            w += align256((size_t)NN * 128 * 8);
    unsigned short* aggb = (unsigned short*)w;  w += align256((size_t)NN * 512 * 2);
    unsigned short* w2t  = (unsigned short*)w;  w += align256((size_t)640 * 64 * 2);
    unsigned short* Tw   = (unsigned short*)w;  w += align256((size_t)26 * 16384 * 2);
    int* perm   = (int*)w;            w += align256((size_t)NN * 4);
    int2* tiles = (int2*)w;           w += align256((size_t)640 * 8);
    int* ntiles = (int*)w;            w += align256(4);

    hipMemsetAsync(cnt, 0, NN * sizeof(int), stream);
    k_hist<<<(EE + 255) / 256, 256, 0, stream>>>(receivers, cnt);
    k_scan<<<1, 1024, 0, stream>>>(cnt, offs, cur);
    k_fill<<<(EE + 255) / 256, 256, 0, stream>>>(receivers, cur, csr);
    k_spec<<<1, 256, 0, stream>>>(specie, perm, tiles, ntiles);
    k_wt<<<(26 * 16384 + 255) / 256, 256, 0, stream>>>(
        W_up_s, W_up_v, W_down_s, W_down_v, W_lin_s, W_lin_v,
        W_skip_s, W_skip_v, Tw);
    k_w2t<<<160, 256, 0, stream>>>(W_rad2, w2t);
    k_pre_mfma<<<NN / 16, 256, 0, stream>>>(node_feats, Tw, h4);
    k_edge_mfma<<<EGRID, 256, 0, stream>>>(vectors, radial, senders, W_rad1,
                                           w2t, h4, offs, csr, aggb);
    k_post_mfma<<<640, 256, 0, stream>>>(node_feats, aggb, perm, tiles, ntiles,
                                         Tw, W_prod_s, W_prod_v, W_ro, out);
}

// Round 9
// 453.892 us; speedup vs baseline: 2.8772x; 1.3167x over previous
//
#include <hip/hip_runtime.h>
#include <hip/hip_bf16.h>

// MACE layer forward, MI355X (gfx950). f32 I/O, bf16 internals.
// Round 9: k_edge sits 4 VGPRs over the 128 occupancy cliff (132 -> 2
// waves/SIMD, Occ 11%, all pipes idle => latency-bound). Cap it at 128 via
// __launch_bounds__(256,2) (empirical cap model from R5: cap=256/arg).
// Side fixes: k_spec tile emission parallelized + merged into k_scan;
// memset+k_wt+k_w2t fused into k_prep (10 -> 7 dispatches).

#define NN 10000
#define EE 320000
#define FEPS 0.17677669529663687f

typedef __attribute__((ext_vector_type(4))) float f32x4;
typedef __attribute__((ext_vector_type(8))) short s16x8;

__device__ __forceinline__ float bflo(unsigned u) { return __uint_as_float(u << 16); }
__device__ __forceinline__ float bfhi(unsigned u) { return __uint_as_float(u & 0xffff0000u); }
__device__ __forceinline__ unsigned short f2bu(float f) {
    unsigned u = __float_as_uint(f);
    return (unsigned short)((u + 0x7FFFu + ((u >> 16) & 1u)) >> 16);
}
__device__ __forceinline__ unsigned pack2(float a, float b) {
    return (unsigned)f2bu(a) | ((unsigned)f2bu(b) << 16);
}
__device__ __forceinline__ s16x8 pack8(float4 a, float4 b) {
    union { s16x8 v; unsigned short u[8]; } r;
    r.u[0] = f2bu(a.x); r.u[1] = f2bu(a.y); r.u[2] = f2bu(a.z); r.u[3] = f2bu(a.w);
    r.u[4] = f2bu(b.x); r.u[5] = f2bu(b.y); r.u[6] = f2bu(b.z); r.u[7] = f2bu(b.w);
    return r.v;
}

// ---------------- CSR build ----------------
__global__ void k_hist(const int* __restrict__ recv, int* __restrict__ cnt) {
    int e = blockIdx.x * blockDim.x + threadIdx.x;
    if (e < EE) {
        int r = recv[e];
        r = ((unsigned)r < NN) ? r : 0;
        atomicAdd(&cnt[r], 1);
    }
}

__global__ void k_fill(const int* __restrict__ recv, int* __restrict__ cur,
                       int* __restrict__ csr) {
    int e = blockIdx.x * blockDim.x + threadIdx.x;
    if (e < EE) {
        int r = recv[e];
        r = ((unsigned)r < NN) ? r : 0;
        int slot = atomicAdd(&cur[r], 1);
        if ((unsigned)slot < EE) csr[slot] = e;
    }
}

// ---- prep: weight tables (26 mats transposed bf16) + w2t + cnt zero ----
// order: 0 up_s, 1 up_v, 2 down_s, 3 down_v, 4 lin_s, 5 lin_v,
//        6..15 skip_s[sp], 16..25 skip_v[sp]
#define TWN (26 * 16384)
#define W2N (640 * 64)
__global__ void k_prep(const float* __restrict__ Wus, const float* __restrict__ Wuv,
                       const float* __restrict__ Wds, const float* __restrict__ Wdv,
                       const float* __restrict__ Wls, const float* __restrict__ Wlv,
                       const float* __restrict__ Wss, const float* __restrict__ Wsv,
                       const float* __restrict__ W_rad2,
                       unsigned short* __restrict__ T,
                       unsigned short* __restrict__ w2t,
                       int* __restrict__ cnt) {
    int idx = blockIdx.x * 256 + threadIdx.x;
    if (idx < TWN) {
        const int m = idx >> 14, p = idx & 16383, d = p >> 7, c = p & 127;
        const float* src;
        if (m == 0) src = Wus; else if (m == 1) src = Wuv;
        else if (m == 2) src = Wds; else if (m == 3) src = Wdv;
        else if (m == 4) src = Wls; else if (m == 5) src = Wlv;
        else if (m < 16) src = Wss + (size_t)(m - 6) * 16384;
        else src = Wsv + (size_t)(m - 16) * 16384;
        T[(size_t)m * 16384 + d * 128 + c] = f2bu(src[c * 128 + d]);
    } else if (idx < TWN + W2N) {
        const int i = idx - TWN;
        const int n = i >> 6, k = i & 63;
        w2t[i] = f2bu(W_rad2[k * 640 + n]);
    } else if (idx < TWN + W2N + NN) {
        cnt[idx - TWN - W2N] = 0;
    }
}

// ---- scan (CSR offsets) + species buckets, one 1024-thread block ----
__global__ __launch_bounds__(1024) void k_scan_spec(
    const int* __restrict__ cnt, int* __restrict__ offs, int* __restrict__ cur,
    const int* __restrict__ specie, int* __restrict__ perm,
    int2* __restrict__ tiles, int* __restrict__ ntiles) {
    __shared__ int sums[1024];
    __shared__ int hcnt[10], hbase[10], hcur[10], tbase[11];
    const int t = threadIdx.x;
    // --- phase A: degree scan ---
    const int chunk = (NN + 1023) / 1024;  // 10
    const int start = t * chunk;
    int local = 0;
    for (int i = 0; i < chunk; i++) {
        int idx = start + i;
        if (idx < NN) local += cnt[idx];
    }
    sums[t] = local;
    __syncthreads();
    for (int ofs = 1; ofs < 1024; ofs <<= 1) {
        int u = (t >= ofs) ? sums[t - ofs] : 0;
        __syncthreads();
        sums[t] += u;
        __syncthreads();
    }
    int base = (t == 0) ? 0 : sums[t - 1];
    for (int i = 0; i < chunk; i++) {
        int idx = start + i;
        if (idx < NN) {
            offs[idx] = base;
            cur[idx] = base;
            base += cnt[idx];
        }
    }
    if (t == 0) offs[NN] = sums[1023];
    // --- phase B: species buckets ---
    if (t < 10) hcnt[t] = 0;
    __syncthreads();
    for (int n = t; n < NN; n += 1024) {
        int s = specie[n];
        s = ((unsigned)s < 10) ? s : 0;
        atomicAdd(&hcnt[s], 1);
    }
    __syncthreads();
    if (t == 0) {
        int run = 0, tc = 0;
        for (int sp = 0; sp < 10; sp++) {
            hbase[sp] = run; hcur[sp] = run; run += hcnt[sp];
            tbase[sp] = tc;  tc += (hcnt[sp] + 15) >> 4;
        }
        tbase[10] = tc;
        *ntiles = tc;
    }
    __syncthreads();
    const int tc = tbase[10];
    for (int ti = t; ti < tc; ti += 1024) {
        int sp = 0;
        while (sp < 9 && ti >= tbase[sp + 1]) sp++;
        const int b = (ti - tbase[sp]) * 16;
        tiles[ti] = make_int2(hbase[sp] + b, (sp << 8) | min(16, hcnt[sp] - b));
    }
    for (int n = t; n < NN; n += 1024) {
        int s = specie[n];
        s = ((unsigned)s < 10) ? s : 0;
        int slot = atomicAdd(&hcur[s], 1);
        if ((unsigned)slot < NN) perm[slot] = n;
    }
}

// ---------------- pre: h = [s,v]@W_up via MFMA -> h4 interleaved ----------
__global__ __launch_bounds__(256) void k_pre_mfma(
    const float* __restrict__ nf,
    const unsigned short* __restrict__ Tw,
    uint2* __restrict__ h4) {
    const int tile = blockIdx.x;  // 625 tiles of 16 nodes
    const int tid = threadIdx.x;
    const int lane = tid & 63, wv = tid >> 6;
    const int col = lane & 15, quad = lane >> 4;
    const int mN = tile * 16 + col;
    const float* rp = nf + (size_t)mN * 512;
    s16x8 Af[4][4];
#pragma unroll
    for (int kt = 0; kt < 4; kt++) {
        const int ko = kt * 32 + quad * 8;
        const float4 fa = *(const float4*)(rp + ko);
        const float4 fb = *(const float4*)(rp + ko + 4);
        Af[0][kt] = pack8(fa, fb);
#pragma unroll
        for (int i = 0; i < 3; i++) {
            union { s16x8 v; unsigned short u[8]; } A;
#pragma unroll
            for (int j = 0; j < 8; j++) A.u[j] = f2bu(rp[128 + 3 * (ko + j) + i]);
            Af[1 + i][kt] = A.v;
        }
    }
    const unsigned short* Ts = Tw;
    const unsigned short* Tv = Tw + 16384;
#pragma unroll
    for (int nt = 0; nt < 2; nt++) {
        const int n0 = 32 * wv + 16 * nt;
        const int d = n0 + col;
        f32x4 C[4];
#pragma unroll
        for (int m = 0; m < 4; m++) C[m] = (f32x4){0.f, 0.f, 0.f, 0.f};
#pragma unroll
        for (int kt = 0; kt < 4; kt++) {
            const int ko = kt * 32 + quad * 8;
            const s16x8 Bs = *(const s16x8*)&Ts[(size_t)d * 128 + ko];
            const s16x8 Bv = *(const s16x8*)&Tv[(size_t)d * 128 + ko];
            C[0] = __builtin_amdgcn_mfma_f32_16x16x32_bf16(Af[0][kt], Bs, C[0], 0, 0, 0);
#pragma unroll
            for (int i = 0; i < 3; i++)
                C[1 + i] = __builtin_amdgcn_mfma_f32_16x16x32_bf16(Af[1 + i][kt], Bv, C[1 + i], 0, 0, 0);
        }
#pragma unroll
        for (int reg = 0; reg < 4; reg++) {
            const int node = tile * 16 + quad * 4 + reg;
            h4[(size_t)node * 128 + d] =
                make_uint2(pack2(C[0][reg], C[1][reg]), pack2(C[2][reg], C[3][reg]));
        }
    }
}

// ------- MFMA edge kernel: grid-stride nodes, cooperative LDS staging ------
// __launch_bounds__(256,2): cap VGPR at 128 (R8 measured 132 -> 2 waves/SIMD
// cliff; cap model from R5: arg=4 gave cap 64 => cap = 256/arg).
#define EGRID 2560
__global__ __launch_bounds__(256, 2) void k_edge_mfma(
    const float* __restrict__ vectors,
    const float* __restrict__ radial,
    const int* __restrict__ senders,
    const float* __restrict__ W_rad1,
    const unsigned short* __restrict__ w2t,   // [640][64] bf16
    const uint2* __restrict__ h4,             // [N][128] {s,v0,v1,v2} bf16
    const int* __restrict__ offs, const int* __restrict__ csr,
    unsigned short* __restrict__ aggb) {      // [N][4][128] bf16 planar
    __shared__ unsigned short w1s[512];
    __shared__ float4 em[64];
    __shared__ float radl[64][8];
    __shared__ unsigned short hid[64 * 72];
    const int tid = threadIdx.x;
    const int lane = tid & 63, wv = tid >> 6;
    const int row = lane & 15, quad = lane >> 4;
    for (int i = tid; i < 512; i += 256) w1s[i] = f2bu(W_rad1[i]);

    s16x8 Bf[2][5][2];
#pragma unroll
    for (int ti = 0; ti < 2; ti++) {
        const int t = 2 * wv + ti;
#pragma unroll
        for (int p = 0; p < 5; p++) {
            const unsigned short* bp =
                w2t + (size_t)(128 * p + 16 * t + row) * 64 + quad * 8;
            Bf[ti][p][0] = *(const s16x8*)(bp);
            Bf[ti][p][1] = *(const s16x8*)(bp + 32);
        }
    }

    for (int n = blockIdx.x; n < NN; n += EGRID) {
        const int start = offs[n];
        const int deg = offs[n + 1] - start;
        float acc_s[2] = {0.f, 0.f}, av0[2] = {0.f, 0.f},
              av1[2] = {0.f, 0.f}, av2[2] = {0.f, 0.f};

        for (int c0 = 0; c0 < deg; c0 += 64) {
            __syncthreads();
            if (tid < 64) {
                const int i = tid, gi = c0 + i;
                if (gi < deg) {
                    int e = csr[start + gi];
                    e = ((unsigned)e < EE) ? e : 0;
                    int j = senders[e];
                    j = ((unsigned)j < NN) ? j : 0;
                    const float vx = vectors[e * 3 + 0];
                    const float vy = vectors[e * 3 + 1];
                    const float vz = vectors[e * 3 + 2];
                    const float inr = 1.7320508075688772f /
                        (sqrtf(vx * vx + vy * vy + vz * vz) + 1e-9f);
                    em[i] = make_float4(__int_as_float(j), vx * inr, vy * inr, vz * inr);
                    *(float4*)&radl[i][0] = *(const float4*)(radial + (size_t)e * 8);
                    *(float4*)&radl[i][4] = *(const float4*)(radial + (size_t)e * 8 + 4);
                } else {
                    em[i] = make_float4(0.f, 0.f, 0.f, 0.f);
                    *(float4*)&radl[i][0] = make_float4(0.f, 0.f, 0.f, 0.f);
                    *(float4*)&radl[i][4] = make_float4(0.f, 0.f, 0.f, 0.f);
                }
            }
            __syncthreads();
            {
                const int eL = tid >> 2, u0 = (tid & 3) * 16;
                float rr[8];
#pragma unroll
                for (int r = 0; r < 8; r++) rr[r] = radl[eL][r];
                float a[16];
#pragma unroll
                for (int u = 0; u < 16; u++) a[u] = 0.f;
#pragma unroll
                for (int r = 0; r < 8; r++) {
                    const uint4 wa = *(const uint4*)&w1s[r * 64 + u0];
                    const uint4 wb = *(const uint4*)&w1s[r * 64 + u0 + 8];
                    const float f = rr[r];
                    a[0] += f * bflo(wa.x);  a[1] += f * bfhi(wa.x);
                    a[2] += f * bflo(wa.y);  a[3] += f * bfhi(wa.y);
                    a[4] += f * bflo(wa.z);  a[5] += f * bfhi(wa.z);
                    a[6] += f * bflo(wa.w);  a[7] += f * bfhi(wa.w);
                    a[8] += f * bflo(wb.x);  a[9] += f * bfhi(wb.x);
                    a[10] += f * bflo(wb.y); a[11] += f * bfhi(wb.y);
                    a[12] += f * bflo(wb.z); a[13] += f * bfhi(wb.z);
                    a[14] += f * bflo(wb.w); a[15] += f * bfhi(wb.w);
                }
                unsigned o[8];
#pragma unroll
                for (int k = 0; k < 8; k++) {
                    const float s0 = a[2 * k] / (1.f + __expf(-a[2 * k]));
                    const float s1 = a[2 * k + 1] / (1.f + __expf(-a[2 * k + 1]));
                    o[k] = pack2(s0, s1);
                }
                *(uint4*)&hid[eL * 72 + u0] = make_uint4(o[0], o[1], o[2], o[3]);
                *(uint4*)&hid[eL * 72 + u0 + 8] = make_uint4(o[4], o[5], o[6], o[7]);
            }
            __syncthreads();
            const int glim = min(64, deg - c0);
            for (int g0 = 0; g0 < glim; g0 += 16) {
                const s16x8 A0 = *(const s16x8*)&hid[(g0 + row) * 72 + quad * 8];
                const s16x8 A1 = *(const s16x8*)&hid[(g0 + row) * 72 + 32 + quad * 8];
                int jr[4]; float yr0[4], yr1[4], yr2[4];
#pragma unroll
                for (int rg = 0; rg < 4; rg++) {
                    const float4 m = em[g0 + quad * 4 + rg];
                    jr[rg] = __float_as_int(m.x);
                    yr0[rg] = m.y; yr1[rg] = m.z; yr2[rg] = m.w;
                }
#pragma unroll
                for (int ti = 0; ti < 2; ti++) {
                    const int c = 16 * (2 * wv + ti) + row;
                    float sj[4], a0r[4], a1r[4], a2r[4], dotr[4],
                          cr0[4], cr1[4], cr2[4];
#pragma unroll
                    for (int rg = 0; rg < 4; rg++) {
                        const uint2 hh = h4[(size_t)jr[rg] * 128 + c];
                        const float s_ = bflo(hh.x), a0 = bfhi(hh.x);
                        const float a1 = bflo(hh.y), a2 = bfhi(hh.y);
                        sj[rg] = s_; a0r[rg] = a0; a1r[rg] = a1; a2r[rg] = a2;
                        dotr[rg] = a0 * yr0[rg] + a1 * yr1[rg] + a2 * yr2[rg];
                        cr0[rg] = a1 * yr2[rg] - a2 * yr1[rg];
                        cr1[rg] = a2 * yr0[rg] - a0 * yr2[rg];
                        cr2[rg] = a0 * yr1[rg] - a1 * yr0[rg];
                    }
#pragma unroll
                    for (int p = 0; p < 5; p++) {
                        f32x4 z = {0.f, 0.f, 0.f, 0.f};
                        z = __builtin_amdgcn_mfma_f32_16x16x32_bf16(A0, Bf[ti][p][0], z, 0, 0, 0);
                        z = __builtin_amdgcn_mfma_f32_16x16x32_bf16(A1, Bf[ti][p][1], z, 0, 0, 0);
#pragma unroll
                        for (int rg = 0; rg < 4; rg++) {
                            const float w = z[rg];
                            if (p == 0) {
                                acc_s[ti] += w * sj[rg];
                            } else if (p == 1) {
                                const float ws = w * sj[rg];
                                av0[ti] += ws * yr0[rg];
                                av1[ti] += ws * yr1[rg];
                                av2[ti] += ws * yr2[rg];
                            } else if (p == 2) {
                                av0[ti] += w * a0r[rg];
                                av1[ti] += w * a1r[rg];
                                av2[ti] += w * a2r[rg];
                            } else if (p == 3) {
                                acc_s[ti] += w * dotr[rg];
                            } else {
                                av0[ti] += w * cr0[rg];
                                av1[ti] += w * cr1[rg];
                                av2[ti] += w * cr2[rg];
                            }
                        }
                    }
                }
            }
        }
#pragma unroll
        for (int ti = 0; ti < 2; ti++) {
            acc_s[ti] += __shfl_xor(acc_s[ti], 16); acc_s[ti] += __shfl_xor(acc_s[ti], 32);
            av0[ti] += __shfl_xor(av0[ti], 16);     av0[ti] += __shfl_xor(av0[ti], 32);
            av1[ti] += __shfl_xor(av1[ti], 16);     av1[ti] += __shfl_xor(av1[ti], 32);
            av2[ti] += __shfl_xor(av2[ti], 16);     av2[ti] += __shfl_xor(av2[ti], 32);
        }
        if (lane < 16) {
            unsigned short* og = aggb + (size_t)n * 512;
#pragma unroll
            for (int ti = 0; ti < 2; ti++) {
                const int c = 16 * (2 * wv + ti) + lane;
                og[c] = f2bu(acc_s[ti]);
                og[128 + c] = f2bu(av0[ti]);
                og[256 + c] = f2bu(av1[ti]);
                og[384 + c] = f2bu(av2[ti]);
            }
        }
    }
}

// -------- post: down+skip GEMM -> prod -> P via LDS -> lin GEMM + out ------
__global__ __launch_bounds__(256) void k_post_mfma(
    const float* __restrict__ nf,
    const unsigned short* __restrict__ aggb,
    const int* __restrict__ perm,
    const int2* __restrict__ tiles,
    const int* __restrict__ ntiles,
    const unsigned short* __restrict__ Tw,
    const float* __restrict__ Wps,
    const float* __restrict__ Wpv,
    const float* __restrict__ Wro,
    float* __restrict__ dout) {
    const int tile = blockIdx.x;
    if (tile >= *ntiles) return;
    const int2 td = tiles[tile];
    const int base = td.x, sp = td.y >> 8, cnt = td.y & 255;
    __shared__ int nodesl[16];
    __shared__ float rol[16];
    __shared__ unsigned short Pl[4][16][128];  // 16 KB
    const int tid = threadIdx.x;
    if (tid < 16) {
        nodesl[tid] = perm[base + ((tid < cnt) ? tid : 0)];
        rol[tid] = 0.f;
    }
    __syncthreads();
    const int lane = tid & 63, wv = tid >> 6;
    const int col = lane & 15, quad = lane >> 4;
    const int aN = nodesl[col];
    const unsigned short* Tds = Tw + (size_t)2 * 16384;
    const unsigned short* Tdv = Tw + (size_t)3 * 16384;
    const unsigned short* Tls = Tw + (size_t)4 * 16384;
    const unsigned short* Tlv = Tw + (size_t)5 * 16384;
    const unsigned short* Tss = Tw + (size_t)(6 + sp) * 16384;
    const unsigned short* Tsv = Tw + (size_t)(16 + sp) * 16384;
    const float* rp = nf + (size_t)aN * 512;
    f32x4 SC[2][4];
#pragma unroll
    for (int nt = 0; nt < 2; nt++) {
        const int n0 = 32 * wv + 16 * nt;
        const int d = n0 + col;
        f32x4 CF[4];
#pragma unroll
        for (int m = 0; m < 4; m++) CF[m] = (f32x4){0.f, 0.f, 0.f, 0.f};
#pragma unroll
        for (int kt = 0; kt < 4; kt++) {
            const int ko = kt * 32 + quad * 8;
            const s16x8 Bs = *(const s16x8*)&Tds[(size_t)d * 128 + ko];
            const s16x8 Bv = *(const s16x8*)&Tdv[(size_t)d * 128 + ko];
#pragma unroll
            for (int m = 0; m < 4; m++) {
                const s16x8 A = *(const s16x8*)&aggb[(size_t)aN * 512 + m * 128 + ko];
                CF[m] = __builtin_amdgcn_mfma_f32_16x16x32_bf16(A, m ? Bv : Bs, CF[m], 0, 0, 0);
            }
        }
        const float wps0 = Wps[sp * 384 + d];
        const float wps1 = Wps[sp * 384 + 128 + d];
        const float wps2 = Wps[sp * 384 + 256 + d];
        const float wpv0 = Wpv[sp * 256 + d];
        const float wpv1 = Wpv[sp * 256 + 128 + d];
#pragma unroll
        for (int reg = 0; reg < 4; reg++) {
            const float fs = CF[0][reg] * FEPS;
            const float f0 = CF[1][reg] * FEPS;
            const float f1 = CF[2][reg] * FEPS;
            const float f2 = CF[3][reg] * FEPS;
            const float ps = fs * wps0 + fs * fs * wps1 + (f0 * f0 + f1 * f1 + f2 * f2) * wps2;
            const float pb = wpv0 + fs * wpv1;
            const int r = quad * 4 + reg;
            Pl[0][r][d] = f2bu(ps);
            Pl[1][r][d] = f2bu(f0 * pb);
            Pl[2][r][d] = f2bu(f1 * pb);
            Pl[3][r][d] = f2bu(f2 * pb);
        }
        f32x4 CS[4];
#pragma unroll
        for (int m = 0; m < 4; m++) CS[m] = (f32x4){0.f, 0.f, 0.f, 0.f};
#pragma unroll
        for (int kt = 0; kt < 4; kt++) {
            const int ko = kt * 32 + quad * 8;
            const s16x8 Bss = *(const s16x8*)&Tss[(size_t)d * 128 + ko];
            const s16x8 Bsv = *(const s16x8*)&Tsv[(size_t)d * 128 + ko];
            const float4 fa = *(const float4*)(rp + ko);
            const float4 fb = *(const float4*)(rp + ko + 4);
            CS[0] = __builtin_amdgcn_mfma_f32_16x16x32_bf16(pack8(fa, fb), Bss, CS[0], 0, 0, 0);
#pragma unroll
            for (int i = 0; i < 3; i++) {
                union { s16x8 v; unsigned short u[8]; } A;
#pragma unroll
                for (int j = 0; j < 8; j++) A.u[j] = f2bu(rp[128 + 3 * (ko + j) + i]);
                CS[1 + i] = __builtin_amdgcn_mfma_f32_16x16x32_bf16(A.v, Bsv, CS[1 + i], 0, 0, 0);
            }
        }
#pragma unroll
        for (int m = 0; m < 4; m++) SC[nt][m] = CS[m];
    }
    __syncthreads();
#pragma unroll
    for (int nt = 0; nt < 2; nt++) {
        const int n0 = 32 * wv + 16 * nt;
        const int d = n0 + col;
        f32x4 CL[4];
#pragma unroll
        for (int m = 0; m < 4; m++) CL[m] = (f32x4){0.f, 0.f, 0.f, 0.f};
#pragma unroll
        for (int kt = 0; kt < 4; kt++) {
            const int ko = kt * 32 + quad * 8;
            const s16x8 Bls = *(const s16x8*)&Tls[(size_t)d * 128 + ko];
            const s16x8 Blv = *(const s16x8*)&Tlv[(size_t)d * 128 + ko];
#pragma unroll
            for (int m = 0; m < 4; m++) {
                const s16x8 A = *(const s16x8*)&Pl[m][col][ko];
                CL[m] = __builtin_amdgcn_mfma_f32_16x16x32_bf16(A, m ? Blv : Bls, CL[m], 0, 0, 0);
            }
        }
        const float wro = Wro[d];
#pragma unroll
        for (int reg = 0; reg < 4; reg++) {
            const int r = quad * 4 + reg;
            if (r < cnt) {
                const int node = nodesl[r];
                const float outs = CL[0][reg] + SC[nt][0][reg];
                const float o0 = CL[1][reg] + SC[nt][1][reg];
                const float o1 = CL[2][reg] + SC[nt][2][reg];
                const float o2 = CL[3][reg] + SC[nt][3][reg];
                float* o = dout + NN + (size_t)node * 512;
                o[d] = outs;
                o[128 + 3 * d + 0] = o0;
                o[128 + 3 * d + 1] = o1;
                o[128 + 3 * d + 2] = o2;
                atomicAdd(&rol[r], outs * wro);
            }
        }
    }
    __syncthreads();
    if (tid < 16 && tid < cnt) dout[nodesl[tid]] = rol[tid];
}

extern "C" void kernel_launch(void* const* d_in, const int* in_sizes, int n_in,
                              void* d_out, int out_size, void* d_ws, size_t ws_size,
                              hipStream_t stream) {
    const float* vectors    = (const float*)d_in[0];
    const float* node_feats = (const float*)d_in[1];
    const int*   specie     = (const int*)d_in[2];
    const float* radial     = (const float*)d_in[3];
    const int*   senders    = (const int*)d_in[4];
    const int*   receivers  = (const int*)d_in[5];
    const float* W_up_s     = (const float*)d_in[6];
    const float* W_up_v     = (const float*)d_in[7];
    const float* W_rad1     = (const float*)d_in[8];
    const float* W_rad2     = (const float*)d_in[9];
    const float* W_down_s   = (const float*)d_in[10];
    const float* W_down_v   = (const float*)d_in[11];
    const float* W_skip_s   = (const float*)d_in[12];
    const float* W_skip_v   = (const float*)d_in[13];
    const float* W_prod_s   = (const float*)d_in[14];
    const float* W_prod_v   = (const float*)d_in[15];
    const float* W_lin_s    = (const float*)d_in[16];
    const float* W_lin_v    = (const float*)d_in[17];
    const float* W_ro       = (const float*)d_in[18];
    float* out = (float*)d_out;

    // workspace carve (~23 MB)
    char* w = (char*)d_ws;
    auto align256 = [](size_t x) { return (x + 255) & ~(size_t)255; };
    int* cnt  = (int*)w;              w += align256((size_t)NN * 4);
    int* offs = (int*)w;              w += align256((size_t)(NN + 1) * 4);
    int* cur  = (int*)w;              w += align256((size_t)NN * 4);
    int* csr  = (int*)w;              w += align256((size_t)EE * 4);
    uint2* h4 = (uint2*)w;            w += align256((size_t)NN * 128 * 8);
    unsigned short* aggb = (unsigned short*)w;  w += align256((size_t)NN * 512 * 2);
    unsigned short* w2t  = (unsigned short*)w;  w += align256((size_t)W2N * 2);
    unsigned short* Tw   = (unsigned short*)w;  w += align256((size_t)TWN * 2);
    int* perm   = (int*)w;            w += align256((size_t)NN * 4);
    int2* tiles = (int2*)w;           w += align256((size_t)640 * 8);
    int* ntiles = (int*)w;            w += align256(4);

    k_prep<<<(TWN + W2N + NN + 255) / 256, 256, 0, stream>>>(
        W_up_s, W_up_v, W_down_s, W_down_v, W_lin_s, W_lin_v,
        W_skip_s, W_skip_v, W_rad2, Tw, w2t, cnt);
    k_hist<<<(EE + 255) / 256, 256, 0, stream>>>(receivers, cnt);
    k_scan_spec<<<1, 1024, 0, stream>>>(cnt, offs, cur, specie, perm, tiles, ntiles);
    k_fill<<<(EE + 255) / 256, 256, 0, stream>>>(receivers, cur, csr);
    k_pre_mfma<<<NN / 16, 256, 0, stream>>>(node_feats, Tw, h4);
    k_edge_mfma<<<EGRID, 256, 0, stream>>>(vectors, radial, senders, W_rad1,
                                           w2t, h4, offs, csr, aggb);
    k_post_mfma<<<640, 256, 0, stream>>>(node_feats, aggb, perm, tiles, ntiles,
                                         Tw, W_prod_s, W_prod_v, W_ro, out);
}